// Round 14
// baseline (555.010 us; speedup 1.0000x reference)
//
#include <hip/hip_runtime.h>
#include <hip/hip_bf16.h>

typedef __bf16 bf16;
typedef bf16 bf16x2 __attribute__((ext_vector_type(2)));
typedef bf16 bf16x4 __attribute__((ext_vector_type(4)));
typedef bf16 bf16x8 __attribute__((ext_vector_type(8)));
typedef float f32x4 __attribute__((ext_vector_type(4)));
typedef float f32x16 __attribute__((ext_vector_type(16)));
typedef unsigned int u32x4 __attribute__((ext_vector_type(4)));

#define HID 1024
#define NHEADS 16
#define HD 64
#define SEQ 4096

__device__ __forceinline__ void gll16(const void* g, void* l) {
  __builtin_amdgcn_global_load_lds(
      (const __attribute__((address_space(1))) void*)g,
      (__attribute__((address_space(3))) void*)l, 16, 0, 0);
}

__device__ __forceinline__ float fast_exp2(float x) {
#if __has_builtin(__builtin_amdgcn_exp2f)
  return __builtin_amdgcn_exp2f(x);
#else
  return __expf(x * 0.6931471805599453f);
#endif
}

// gfx950 half-wave swap: X' = [X.lo | Y.lo], Y' = [X.hi | Y.hi]
__device__ __forceinline__ void pl32swap(unsigned& a, unsigned& b) {
  asm volatile("v_permlane32_swap_b32 %0, %1" : "+v"(a), "+v"(b));
}

// ---------------------------------------------------------------------------
// Prep: z=0 convert X fp32->bf16; z=1..4 transpose+convert W -> Wt[out][in].
// Attention scale folded into Wq in LOG2 domain: 0.125 * log2(e).
// ---------------------------------------------------------------------------
__global__ __launch_bounds__(256)
void prep_kernel(const float* __restrict__ X,
                 const float* __restrict__ Wq, const float* __restrict__ Wk,
                 const float* __restrict__ Wv, const float* __restrict__ Wo,
                 bf16* __restrict__ Xb, bf16* __restrict__ Wt)
{
  const int z = blockIdx.z, t = threadIdx.x, bx = blockIdx.x;
  if (z == 0) {
    const float4* src = (const float4*)X;
    const int gid = bx * 256 + t;
    #pragma unroll
    for (int i = 0; i < 16; ++i) {
      float4 v = src[gid + i * 65536];
      bf16x4 o = {(bf16)v.x, (bf16)v.y, (bf16)v.z, (bf16)v.w};
      *(bf16x4*)&Xb[(size_t)(gid + i * 65536) * 4] = o;
    }
  } else {
    const float* W = (z == 1) ? Wq : (z == 2) ? Wk : (z == 3) ? Wv : Wo;
    bf16* dst = Wt + (size_t)(z - 1) * HID * HID;
    const float scale = (z == 1) ? 0.18033688011112042f : 1.0f;  // 0.125*log2(e)
    __shared__ bf16 T[64][68];
    const int tr = (bx >> 4) * 64, tc = (bx & 15) * 64;
    #pragma unroll
    for (int p = 0; p < 4; ++p) {
      int row = (t >> 4) + p * 16;
      float4 v = *(const float4*)&W[(size_t)(tr + row) * HID + tc + (t & 15) * 4];
      T[row][(t & 15) * 4 + 0] = (bf16)(v.x * scale);
      T[row][(t & 15) * 4 + 1] = (bf16)(v.y * scale);
      T[row][(t & 15) * 4 + 2] = (bf16)(v.z * scale);
      T[row][(t & 15) * 4 + 3] = (bf16)(v.w * scale);
    }
    __syncthreads();
    #pragma unroll
    for (int p = 0; p < 4; ++p) {
      int rp = (t >> 4) + p * 16;
      int cb = (t & 15) * 4;
      bf16x4 o = {T[cb + 0][rp], T[cb + 1][rp], T[cb + 2][rp], T[cb + 3][rp]};
      *(bf16x4*)&dst[(size_t)(tc + rp) * HID + tr + cb] = o;
    }
  }
}

// ---------------------------------------------------------------------------
// QKV GEMM: C = Xb[M,K] @ Wt[z][N,K]^T. 128x128 tile, BK=64, global_load_lds
// staging with chunk-rotation swizzle. z=2 writes V transposed (Vt[hid][seq]).
// ---------------------------------------------------------------------------
__global__ __launch_bounds__(256)
void qkv_gemm(const bf16* __restrict__ A, const bf16* __restrict__ Wt,
              bf16* __restrict__ Qg, bf16* __restrict__ Kg,
              bf16* __restrict__ Vt)
{
  __shared__ bf16 sbuf[16384];
  bf16* As = sbuf;
  bf16* Bs = sbuf + 8192;

  const int t = threadIdx.x, lane = t & 63, w = t >> 6;
  const int z = blockIdx.z;
  const int n0 = blockIdx.x * 128, m0 = blockIdx.y * 128;
  const bf16* Bt = Wt + (size_t)z * HID * HID;
  const int wm = (w & 1) * 64, wn = (w >> 1) * 64;
  const int fr = lane & 15, quad = lane >> 4;

  f32x4 acc[4][4] = {};

  const int sr = lane >> 3;              // 0..7
  const int sc = ((lane & 7) - sr) & 7;  // rotated chunk
  const bf16* ga = A  + (size_t)(m0 + w * 32 + sr) * HID + sc * 8;
  const bf16* gb = Bt + (size_t)(n0 + w * 32 + sr) * HID + sc * 8;

  for (int k0 = 0; k0 < HID; k0 += 64) {
    __syncthreads();
    #pragma unroll
    for (int c = 0; c < 4; ++c) {
      gll16(ga + (size_t)(c * 8) * HID + k0, As + (w * 32 + c * 8) * 64);
      gll16(gb + (size_t)(c * 8) * HID + k0, Bs + (w * 32 + c * 8) * 64);
    }
    __syncthreads();
    #pragma unroll
    for (int ks = 0; ks < 2; ++ks) {
      bf16x8 af[4], bg[4];
      #pragma unroll
      for (int i = 0; i < 4; ++i)
        af[i] = *(const bf16x8*)&As[(wm + i * 16 + fr) * 64 +
                                    ((ks * 4 + quad + fr) & 7) * 8];
      #pragma unroll
      for (int i = 0; i < 4; ++i)
        bg[i] = *(const bf16x8*)&Bs[(wn + i * 16 + fr) * 64 +
                                    ((ks * 4 + quad + fr) & 7) * 8];
      #pragma unroll
      for (int mi = 0; mi < 4; ++mi)
        #pragma unroll
        for (int ni = 0; ni < 4; ++ni)
          acc[mi][ni] = __builtin_amdgcn_mfma_f32_16x16x32_bf16(
              af[mi], bg[ni], acc[mi][ni], 0, 0, 0);
    }
  }

  if (z < 2) {
    bf16* C = z ? Kg : Qg;
    #pragma unroll
    for (int mi = 0; mi < 4; ++mi)
      #pragma unroll
      for (int ni = 0; ni < 4; ++ni)
        #pragma unroll
        for (int r = 0; r < 4; ++r)
          C[(size_t)(m0 + wm + mi * 16 + quad * 4 + r) * HID +
            n0 + wn + ni * 16 + fr] = (bf16)acc[mi][ni][r];
  } else {
    __syncthreads();
    // swizzled transpose: col stored at (col + 8*(row&15)) & 127
    #pragma unroll
    for (int mi = 0; mi < 4; ++mi)
      #pragma unroll
      for (int ni = 0; ni < 4; ++ni)
        #pragma unroll
        for (int r = 0; r < 4; ++r) {
          int row = wn + ni * 16 + fr;
          int col = wm + mi * 16 + quad * 4 + r;
          int colS = (col + 8 * (row & 15)) & 127;
          sbuf[row * 128 + colS] = (bf16)acc[mi][ni][r];
        }
    __syncthreads();
    const int row = t >> 1, cb = (t & 1) * 64;
    #pragma unroll
    for (int j = 0; j < 8; ++j) {
      int c0 = (cb + j * 8 + 8 * (row & 15)) & 127;
      *(bf16x8*)&Vt[(size_t)(n0 + row) * SEQ + m0 + cb + j * 8] =
          *(const bf16x8*)&sbuf[row * 128 + c0];
    }
  }
}

// ---------------------------------------------------------------------------
// O-projection: out = Og[M,K] @ Wto[N,K]^T, fp32 out. Same swizzled staging.
// ---------------------------------------------------------------------------
__global__ __launch_bounds__(256)
void oproj_gemm(const bf16* __restrict__ A, const bf16* __restrict__ Bt,
                float* __restrict__ C)
{
  __shared__ bf16 sbuf[16384];
  bf16* As = sbuf;
  bf16* Bs = sbuf + 8192;

  const int t = threadIdx.x, lane = t & 63, w = t >> 6;
  const int n0 = blockIdx.x * 128, m0 = blockIdx.y * 128;
  const int wm = (w & 1) * 64, wn = (w >> 1) * 64;
  const int fr = lane & 15, quad = lane >> 4;

  f32x4 acc[4][4] = {};

  const int sr = lane >> 3;
  const int sc = ((lane & 7) - sr) & 7;
  const bf16* ga = A  + (size_t)(m0 + w * 32 + sr) * HID + sc * 8;
  const bf16* gb = Bt + (size_t)(n0 + w * 32 + sr) * HID + sc * 8;

  for (int k0 = 0; k0 < HID; k0 += 64) {
    __syncthreads();
    #pragma unroll
    for (int c = 0; c < 4; ++c) {
      gll16(ga + (size_t)(c * 8) * HID + k0, As + (w * 32 + c * 8) * 64);
      gll16(gb + (size_t)(c * 8) * HID + k0, Bs + (w * 32 + c * 8) * 64);
    }
    __syncthreads();
    #pragma unroll
    for (int ks = 0; ks < 2; ++ks) {
      bf16x8 af[4], bg[4];
      #pragma unroll
      for (int i = 0; i < 4; ++i)
        af[i] = *(const bf16x8*)&As[(wm + i * 16 + fr) * 64 +
                                    ((ks * 4 + quad + fr) & 7) * 8];
      #pragma unroll
      for (int i = 0; i < 4; ++i)
        bg[i] = *(const bf16x8*)&Bs[(wn + i * 16 + fr) * 64 +
                                    ((ks * 4 + quad + fr) & 7) * 8];
      #pragma unroll
      for (int mi = 0; mi < 4; ++mi)
        #pragma unroll
        for (int ni = 0; ni < 4; ++ni)
          acc[mi][ni] = __builtin_amdgcn_mfma_f32_16x16x32_bf16(
              af[mi], bg[ni], acc[mi][ni], 0, 0, 0);
    }
  }

  #pragma unroll
  for (int mi = 0; mi < 4; ++mi)
    #pragma unroll
    for (int ni = 0; ni < 4; ++ni)
      #pragma unroll
      for (int r = 0; r < 4; ++r)
        C[(size_t)(m0 + wm + mi * 16 + quad * 4 + r) * HID +
          n0 + wn + ni * 16 + fr] = acc[mi][ni][r];
}

// ---------------------------------------------------------------------------
// Attention v14: attn13 + dependency-chain splitting (latency-bound per r13:
// wall/iter 429 cyc ~= serial chain ~400 cyc, all pipes <50%).
// - QK: 2 independent 2-deep mfma chains (sa: j=0,1; sb: j=2,3), merged with
//   16 VALU adds -- halves the 4-deep C-accumulation serial chain.
// - PV: dual accumulators accO/accO2 per db (av0 -> accO, av1 -> accO2),
//   folded once at epilogue -- halves loop-carried PV chain.
// VGPR ~112 < 128 cap at (256,4); spill tripwire: WRITE_SIZE must stay 34MB.
// Rest identical to attn13 (exp2-direct, den-on-MFMA, permlane32 exchange).
// ---------------------------------------------------------------------------
__global__ __launch_bounds__(256, 4)
void attn14(const bf16* __restrict__ Q, const bf16* __restrict__ K,
            const bf16* __restrict__ Vt, bf16* __restrict__ Opart,
            float* __restrict__ Den)
{
  __shared__ bf16 Ks[2][4096];
  __shared__ bf16 Vs[2][4096];

  const int t = threadIdx.x, lane = t & 63, w = t >> 6;
  const int h = blockIdx.y, q0 = blockIdx.x * 128, qtr = blockIdx.z;
  const int q = lane & 31, hi = lane >> 5;
  const int qrow = q0 + w * 32 + q;

  // Q B-fragments: bq[j] = Q[qrow][h*64 + j*16 + hi*8 .. +8]
  bf16x8 bq[4];
  #pragma unroll
  for (int j = 0; j < 4; ++j)
    bq[j] = *(const bf16x8*)&Q[(size_t)qrow * HID + h * 64 + j * 16 + hi * 8];

  const bf16 onev = (bf16)1.0f;
  const bf16x8 ones = {onev, onev, onev, onev, onev, onev, onev, onev};

  const int sr = lane >> 3;
  const int sc = ((lane & 7) - sr) & 7;
  const bf16* gk = K  + (size_t)(qtr * 1024 + w * 16 + sr) * HID + h * 64 + sc * 8;
  const bf16* gv = Vt + (size_t)(h * 64 + w * 16 + sr) * SEQ + qtr * 1024 + sc * 8;

  #pragma unroll
  for (int j = 0; j < 2; ++j) {
    gll16(gk + (size_t)(j * 8) * HID, &Ks[0][(w * 16 + j * 8) * 64]);
    gll16(gv + (size_t)(j * 8) * SEQ, &Vs[0][(w * 16 + j * 8) * 64]);
  }

  f32x16 accO[2], accO2[2], accD;
  #pragma unroll
  for (int r = 0; r < 16; ++r) {
    accO[0][r] = 0.f; accO[1][r] = 0.f;
    accO2[0][r] = 0.f; accO2[1][r] = 0.f;
    accD[r] = 0.f;
  }
  float m4[4] = {-3e38f, -3e38f, -3e38f, -3e38f};

  __syncthreads();

  for (int kk = 0; kk < 16; ++kk) {
    const int buf = kk & 1;
    if (kk < 15) {
      const size_t key0n = (size_t)(kk + 1) * 64;
      #pragma unroll
      for (int j = 0; j < 2; ++j) {
        gll16(gk + (key0n + j * 8) * HID, &Ks[buf ^ 1][(w * 16 + j * 8) * 64]);
        gll16(gv + key0n + (size_t)(j * 8) * SEQ,
              &Vs[buf ^ 1][(w * 16 + j * 8) * 64]);
      }
    }

    #pragma unroll
    for (int st = 0; st < 2; ++st) {
      const int r0 = st * 32;         // key sub-tile base row
      const int row = r0 + q;
      // QK^T: two independent 2-deep mfma chains, merged on VALU
      f32x16 sa, sb;
      #pragma unroll
      for (int r = 0; r < 16; ++r) { sa[r] = 0.f; sb[r] = 0.f; }
      {
        bf16x8 ak0 = *(const bf16x8*)&Ks[buf][row * 64 + ((0 + hi + row) & 7) * 8];
        sa = __builtin_amdgcn_mfma_f32_32x32x16_bf16(ak0, bq[0], sa, 0, 0, 0);
        bf16x8 ak2 = *(const bf16x8*)&Ks[buf][row * 64 + ((4 + hi + row) & 7) * 8];
        sb = __builtin_amdgcn_mfma_f32_32x32x16_bf16(ak2, bq[2], sb, 0, 0, 0);
        bf16x8 ak1 = *(const bf16x8*)&Ks[buf][row * 64 + ((2 + hi + row) & 7) * 8];
        sa = __builtin_amdgcn_mfma_f32_32x32x16_bf16(ak1, bq[1], sa, 0, 0, 0);
        bf16x8 ak3 = *(const bf16x8*)&Ks[buf][row * 64 + ((6 + hi + row) & 7) * 8];
        sb = __builtin_amdgcn_mfma_f32_32x32x16_bf16(ak3, bq[3], sb, 0, 0, 0);
      }
      f32x16 s;
      #pragma unroll
      for (int r = 0; r < 16; ++r) s[r] = sa[r] + sb[r];

      // running block-max: 3-input max chains (v_max3)
      #pragma unroll
      for (int r = 0; r < 16; r += 4) {
        m4[0] = fmaxf(fmaxf(m4[0], s[r]), s[r + 1]);
        m4[1] = fmaxf(fmaxf(m4[1], s[r + 2]), s[r + 3]);
      }

      // P = exp2(s) directly; den handled by MFMA below
      float p[16];
      #pragma unroll
      for (int r = 0; r < 16; ++r) p[r] = fast_exp2(s[r]);

      unsigned pk[8];
      #pragma unroll
      for (int i = 0; i < 8; ++i) {
        bf16x2 pp = {(bf16)p[2 * i], (bf16)p[2 * i + 1]};
        pk[i] = __builtin_bit_cast(unsigned, pp);
      }
      // half-wave exchange on VALU: post-swap pk[] is the fragment verbatim
      pl32swap(pk[0], pk[2]);
      pl32swap(pk[1], pk[3]);
      pl32swap(pk[4], pk[6]);
      pl32swap(pk[5], pk[7]);
      u32x4 w0 = {pk[0], pk[1], pk[2], pk[3]};
      u32x4 w1 = {pk[4], pk[5], pk[6], pk[7]};
      bf16x8 bp0 = __builtin_bit_cast(bf16x8, w0);
      bf16x8 bp1 = __builtin_bit_cast(bf16x8, w1);

      // den on the MFMA pipe: every row of accD = sum_k P[q][k]
      accD = __builtin_amdgcn_mfma_f32_32x32x16_bf16(ones, bp0, accD, 0, 0, 0);
      accD = __builtin_amdgcn_mfma_f32_32x32x16_bf16(ones, bp1, accD, 0, 0, 0);

      // PV with dual accumulators: av0 -> accO, av1 -> accO2
      #pragma unroll
      for (int db = 0; db < 2; ++db) {
        const int rowd = db * 32 + q;
        bf16x8 av0 = *(const bf16x8*)&Vs[buf][rowd * 64 +
                       ((st * 4 + 0 + hi + rowd) & 7) * 8];
        accO[db] = __builtin_amdgcn_mfma_f32_32x32x16_bf16(av0, bp0, accO[db], 0, 0, 0);
        bf16x8 av1 = *(const bf16x8*)&Vs[buf][rowd * 64 +
                       ((st * 4 + 2 + hi + rowd) & 7) * 8];
        accO2[db] = __builtin_amdgcn_mfma_f32_32x32x16_bf16(av1, bp1, accO2[db], 0, 0, 0);
      }
    }
    __syncthreads();
  }

  // epilogue: fold dual accumulators, merge block max, write partials
  {
    #pragma unroll
    for (int db = 0; db < 2; ++db)
      #pragma unroll
      for (int r = 0; r < 16; ++r) accO[db][r] += accO2[db][r];

    const float l = accD[0];
    float m_true = fmaxf(fmaxf(m4[0], m4[1]), fmaxf(m4[2], m4[3]));
    m_true = fmaxf(m_true, __shfl_xor(m_true, 32));
    const float inv = 1.0f / l;
    const size_t base =
        ((size_t)(qtr * 16 + h) * 128 + (q0 >> 5) + w) * 2048 + (size_t)lane * 32;
    #pragma unroll
    for (int j = 0; j < 4; ++j) {
      bf16x8 wv;
      #pragma unroll
      for (int e = 0; e < 8; ++e)
        wv[e] = (bf16)(accO[j >> 1][(j & 1) * 8 + e] * inv);
      *(bf16x8*)&Opart[base + j * 8] = wv;
    }
    if (hi == 0)
      Den[(size_t)(qtr * 16 + h) * SEQ + qrow] = l * fast_exp2(-m_true);
  }
}

// ---------------------------------------------------------------------------
// Combine8: one wave per (h, 32-query seg). Reads 4 lane-major partials
// (coalesced), weights by den_rb / sum(den), LDS-transposes reg layout
// (d = db*32 + (r&3) + 8*(r>>2) + 4*hi) to [q][d], writes Og coalesced.
// ---------------------------------------------------------------------------
__global__ __launch_bounds__(64)
void combine8(const bf16* __restrict__ Opart, const float* __restrict__ Den,
              bf16* __restrict__ Og)
{
  __shared__ bf16 T[32][72];
  const int lane = threadIdx.x & 63;
  const int h = blockIdx.y, qs = blockIdx.x;   // qs in [0,128)
  const int q = lane & 31, hi = lane >> 5;

  float dw[4];
  #pragma unroll
  for (int rb = 0; rb < 4; ++rb)
    dw[rb] = Den[(size_t)(rb * 16 + h) * SEQ + qs * 32 + q];
  const float inv = 1.0f / (dw[0] + dw[1] + dw[2] + dw[3]);

  float acc[32];
  #pragma unroll
  for (int i = 0; i < 32; ++i) acc[i] = 0.f;
  #pragma unroll
  for (int rb = 0; rb < 4; ++rb) {
    const float wq = dw[rb] * inv;
    const size_t base =
        ((size_t)(rb * 16 + h) * 128 + qs) * 2048 + (size_t)lane * 32;
    #pragma unroll
    for (int j = 0; j < 4; ++j) {
      bf16x8 v = *(const bf16x8*)&Opart[base + j * 8];
      #pragma unroll
      for (int e = 0; e < 8; ++e) acc[j * 8 + e] += wq * (float)v[e];
    }
  }

  #pragma unroll
  for (int idx = 0; idx < 32; ++idx) {
    const int db = idx >> 4, r = idx & 15;
    const int d = db * 32 + (r & 3) + 8 * (r >> 2) + 4 * hi;
    T[q][d] = (bf16)acc[idx];
  }
  __syncthreads();
  #pragma unroll
  for (int p = 0; p < 4; ++p) {
    const int row = p * 8 + (lane >> 3);
    *(bf16x8*)&Og[(size_t)(qs * 32 + row) * HID + h * 64 + (lane & 7) * 8] =
        *(const bf16x8*)&T[row][(lane & 7) * 8];
  }
}

// ---------------------------------------------------------------------------
// Attention v5 (fallback if workspace < 81 MB): round-3-verified.
// ---------------------------------------------------------------------------
#define THR_L2 12.0f

__global__ __launch_bounds__(256, 2)
void attn5(const bf16* __restrict__ Q, const bf16* __restrict__ K,
           const bf16* __restrict__ Vt, bf16* __restrict__ O)
{
  __shared__ bf16 Ks[2][4096];
  __shared__ bf16 Vs[2][4096];
  __shared__ bf16 Ps[4][1024];

  const int t = threadIdx.x, lane = t & 63, w = t >> 6;
  const int h = blockIdx.y, q0 = blockIdx.x * 128;
  const int fr = lane & 15, quad = lane >> 4;

  bf16x8 bq[2][2];
  #pragma unroll
  for (int qf = 0; qf < 2; ++qf)
    #pragma unroll
    for (int ks = 0; ks < 2; ++ks)
      bq[qf][ks] = *(const bf16x8*)&Q[(size_t)(q0 + w * 32 + qf * 16 + fr) * HID
                                      + h * 64 + ks * 32 + quad * 8];

  const int sr = lane >> 3;
  const int sc = ((lane & 7) - sr) & 7;
  const bf16* gk = K  + (size_t)(w * 16 + sr) * HID + h * 64 + sc * 8;
  const bf16* gv = Vt + (size_t)(h * 64 + w * 16 + sr) * SEQ + sc * 8;

  #pragma unroll
  for (int j = 0; j < 2; ++j) {
    gll16(gk + (size_t)(j * 8) * HID, &Ks[0][(w * 16 + j * 8) * 64]);
    gll16(gv + (size_t)(j * 8) * SEQ, &Vs[0][(w * 16 + j * 8) * 64]);
  }

  f32x4 accN[2][4] = {};
  f32x4 accO[2][4] = {};
  float m_used[2] = {-3e38f, -3e38f}, m_true[2] = {-3e38f, -3e38f};
  float l_i[2] = {0.f, 0.f}, den[2] = {0.f, 0.f};

  __syncthreads();

  for (int kk = 0; kk < 64; ++kk) {
    const int buf = kk & 1;
    if (kk < 63) {
      const size_t key0n = (size_t)(kk + 1) * 64;
      #pragma unroll
      for (int j = 0; j < 2; ++j) {
        gll16(gk + (key0n + j * 8) * HID, &Ks[buf ^ 1][(w * 16 + j * 8) * 64]);
        gll16(gv + key0n + (size_t)(j * 8) * SEQ,
              &Vs[buf ^ 1][(w * 16 + j * 8) * 64]);
      }
    }

    bf16x8 ak[4][2];
    #pragma unroll
    for (int mt = 0; mt < 4; ++mt)
      #pragma unroll
      for (int ks = 0; ks < 2; ++ks)
        ak[mt][ks] = *(const bf16x8*)&Ks[buf][(mt * 16 + fr) * 64 +
                                             ((ks * 4 + quad + fr) & 7) * 8];

    f32x4 s[2][4];
    #pragma unroll
    for (int qf = 0; qf < 2; ++qf)
      #pragma unroll
      for (int mt = 0; mt < 4; ++mt) {
        f32x4 z = {};
        z = __builtin_amdgcn_mfma_f32_16x16x32_bf16(ak[mt][0], bq[qf][0], z, 0, 0, 0);
        z = __builtin_amdgcn_mfma_f32_16x16x32_bf16(ak[mt][1], bq[qf][1], z, 0, 0, 0);
        s[qf][mt] = z;
      }

    bf16x8 bp[2][2];
    #pragma unroll
    for (int qf = 0; qf < 2; ++qf) {
      float mx0 = fmaxf(fmaxf(s[qf][0][0], s[qf][0][1]), fmaxf(s[qf][0][2], s[qf][0][3]));
      float mx1 = fmaxf(fmaxf(s[qf][1][0], s[qf][1][1]), fmaxf(s[qf][1][2], s[qf][1][3]));
      float mx2 = fmaxf(fmaxf(s[qf][2][0], s[qf][2][1]), fmaxf(s[qf][2][2], s[qf][2][3]));
      float mx3 = fmaxf(fmaxf(s[qf][3][0], s[qf][3][1]), fmaxf(s[qf][3][2], s[qf][3][3]));
      float mx = fmaxf(fmaxf(mx0, mx1), fmaxf(mx2, mx3));
      mx = fmaxf(mx, __shfl_xor(mx, 16));
      mx = fmaxf(mx, __shfl_xor(mx, 32));
      m_true[qf] = fmaxf(m_true[qf], mx);

      if (__any(mx > m_used[qf] + THR_L2)) {
        const float mn = fmaxf(m_used[qf], mx);
        const float a = fast_exp2(m_used[qf] - mn);
        m_used[qf] = mn;
        l_i[qf] *= a;
        #pragma unroll
        for (int dt = 0; dt < 4; ++dt) accO[qf][dt] *= a;
      }

      float sum = 0.f;
      const int prow = fr * 64;
      #pragma unroll
      for (int mt = 0; mt < 4; ++mt) {
        float p0 = fast_exp2(s[qf][mt][0] - m_used[qf]);
        float p1 = fast_exp2(s[qf][mt][1] - m_used[qf]);
        float p2 = fast_exp2(s[qf][mt][2] - m_used[qf]);
        float p3 = fast_exp2(s[qf][mt][3] - m_used[qf]);
        sum += (p0 + p1) + (p2 + p3);
        bf16x4 pv = {(bf16)p0, (bf16)p1, (bf16)p2, (bf16)p3};
        *(bf16x4*)&Ps[w][prow + ((mt * 2 + (quad >> 1) + fr) & 7) * 8 +
                         (quad & 1) * 4] = pv;
      }
      sum += __shfl_xor(sum, 16);
      sum += __shfl_xor(sum, 32);
      l_i[qf] += sum;

      #pragma unroll
      for (int ks = 0; ks < 2; ++ks)
        bp[qf][ks] = *(const bf16x8*)&Ps[w][fr * 64 +
                                            ((ks * 4 + quad + fr) & 7) * 8];
    }

    #pragma unroll
    for (int ks = 0; ks < 2; ++ks)
      #pragma unroll
      for (int dt = 0; dt < 4; ++dt) {
        bf16x8 av = *(const bf16x8*)&Vs[buf][(dt * 16 + fr) * 64 +
                                            ((ks * 4 + quad + fr) & 7) * 8];
        accO[0][dt] = __builtin_amdgcn_mfma_f32_16x16x32_bf16(av, bp[0][ks], accO[0][dt], 0, 0, 0);
        accO[1][dt] = __builtin_amdgcn_mfma_f32_16x16x32_bf16(av, bp[1][ks], accO[1][dt], 0, 0, 0);
      }

    if ((kk & 15) == 15) {
      #pragma unroll
      for (int qf = 0; qf < 2; ++qf) {
        const float c = fast_exp2(m_used[qf] - m_true[qf]);
        den[qf] += l_i[qf] * c;
        #pragma unroll
        for (int dt = 0; dt < 4; ++dt)
          #pragma unroll
          for (int r = 0; r < 4; ++r) accN[qf][dt][r] += accO[qf][dt][r] * c;
        #pragma unroll
        for (int dt = 0; dt < 4; ++dt) accO[qf][dt] = (f32x4){0.f, 0.f, 0.f, 0.f};
        l_i[qf] = 0.f; m_used[qf] = -3e38f; m_true[qf] = -3e38f;
      }
    }
    __syncthreads();
  }

  #pragma unroll
  for (int qf = 0; qf < 2; ++qf) {
    const float inv = 1.0f / den[qf];
    const size_t orow = (size_t)(q0 + w * 32 + qf * 16 + fr) * HID + h * 64;
    #pragma unroll
    for (int dt = 0; dt < 4; ++dt) {
      bf16x4 ov = {(bf16)(accN[qf][dt][0] * inv), (bf16)(accN[qf][dt][1] * inv),
                   (bf16)(accN[qf][dt][2] * inv), (bf16)(accN[qf][dt][3] * inv)};
      *(bf16x4*)&O[orow + dt * 16 + quad * 4] = ov;
    }
  }
}

extern "C" void kernel_launch(void* const* d_in, const int* in_sizes, int n_in,
                              void* d_out, int out_size, void* d_ws, size_t ws_size,
                              hipStream_t stream)
{
  const float* X  = (const float*)d_in[0];
  const float* Wq = (const float*)d_in[1];
  const float* Wk = (const float*)d_in[2];
  const float* Wv = (const float*)d_in[3];
  const float* Wo = (const float*)d_in[4];
  float* out = (float*)d_out;

  const size_t MB = 1024 * 1024;
  bf16*  Xb  = (bf16*)d_ws;                       // 8 MB
  bf16*  Wt  = (bf16*)((char*)d_ws + 8  * MB);    // 4 x 2 MB
  bf16*  Qg  = (bf16*)((char*)d_ws + 16 * MB);    // 8 MB
  bf16*  Kg  = (bf16*)((char*)d_ws + 24 * MB);    // 8 MB
  bf16*  Vtg = (bf16*)((char*)d_ws + 32 * MB);    // 8 MB, [hid][seq]
  bf16*  Og  = (bf16*)((char*)d_ws + 40 * MB);    // 8 MB
  bf16*  Opart = (bf16*)((char*)d_ws + 48 * MB);  // 32 MB lane-major partials
  float* Den   = (float*)((char*)d_ws + 80 * MB); // 1 MB fp32

  prep_kernel<<<dim3(256, 1, 5), 256, 0, stream>>>(X, Wq, Wk, Wv, Wo, Xb, Wt);
  qkv_gemm<<<dim3(HID / 128, SEQ / 128, 3), 256, 0, stream>>>(Xb, Wt, Qg, Kg, Vtg);
  if (ws_size >= 81 * MB) {
    attn14<<<dim3(SEQ / 128, NHEADS, 4), 256, 0, stream>>>(Qg, Kg, Vtg, Opart, Den);
    combine8<<<dim3(SEQ / 32, NHEADS), 64, 0, stream>>>(Opart, Den, Og);
  } else {
    attn5<<<dim3(SEQ / 128, NHEADS), 256, 0, stream>>>(Qg, Kg, Vtg, Og);
  }
  oproj_gemm<<<dim3(HID / 128, SEQ / 128), 256, 0, stream>>>(
      Og, Wt + (size_t)3 * HID * HID, out);
}

// Round 15
// 237.250 us; speedup vs baseline: 2.3393x; 2.3393x over previous
//
#include <hip/hip_runtime.h>
#include <hip/hip_bf16.h>

typedef __bf16 bf16;
typedef bf16 bf16x2 __attribute__((ext_vector_type(2)));
typedef bf16 bf16x4 __attribute__((ext_vector_type(4)));
typedef bf16 bf16x8 __attribute__((ext_vector_type(8)));
typedef float f32x4 __attribute__((ext_vector_type(4)));
typedef float f32x16 __attribute__((ext_vector_type(16)));
typedef unsigned int u32x4 __attribute__((ext_vector_type(4)));

#define HID 1024
#define NHEADS 16
#define HD 64
#define SEQ 4096

__device__ __forceinline__ void gll16(const void* g, void* l) {
  __builtin_amdgcn_global_load_lds(
      (const __attribute__((address_space(1))) void*)g,
      (__attribute__((address_space(3))) void*)l, 16, 0, 0);
}

__device__ __forceinline__ float fast_exp2(float x) {
#if __has_builtin(__builtin_amdgcn_exp2f)
  return __builtin_amdgcn_exp2f(x);
#else
  return __expf(x * 0.6931471805599453f);
#endif
}

// gfx950 half-wave swap: X' = [X.lo | Y.lo], Y' = [X.hi | Y.hi]
__device__ __forceinline__ void pl32swap(unsigned& a, unsigned& b) {
  asm volatile("v_permlane32_swap_b32 %0, %1" : "+v"(a), "+v"(b));
}

// ---------------------------------------------------------------------------
// Prep: z=0 convert X fp32->bf16; z=1..4 transpose+convert W -> Wt[out][in].
// Attention scale folded into Wq in LOG2 domain: 0.125 * log2(e).
// ---------------------------------------------------------------------------
__global__ __launch_bounds__(256)
void prep_kernel(const float* __restrict__ X,
                 const float* __restrict__ Wq, const float* __restrict__ Wk,
                 const float* __restrict__ Wv, const float* __restrict__ Wo,
                 bf16* __restrict__ Xb, bf16* __restrict__ Wt)
{
  const int z = blockIdx.z, t = threadIdx.x, bx = blockIdx.x;
  if (z == 0) {
    const float4* src = (const float4*)X;
    const int gid = bx * 256 + t;
    #pragma unroll
    for (int i = 0; i < 16; ++i) {
      float4 v = src[gid + i * 65536];
      bf16x4 o = {(bf16)v.x, (bf16)v.y, (bf16)v.z, (bf16)v.w};
      *(bf16x4*)&Xb[(size_t)(gid + i * 65536) * 4] = o;
    }
  } else {
    const float* W = (z == 1) ? Wq : (z == 2) ? Wk : (z == 3) ? Wv : Wo;
    bf16* dst = Wt + (size_t)(z - 1) * HID * HID;
    const float scale = (z == 1) ? 0.18033688011112042f : 1.0f;  // 0.125*log2(e)
    __shared__ bf16 T[64][68];
    const int tr = (bx >> 4) * 64, tc = (bx & 15) * 64;
    #pragma unroll
    for (int p = 0; p < 4; ++p) {
      int row = (t >> 4) + p * 16;
      float4 v = *(const float4*)&W[(size_t)(tr + row) * HID + tc + (t & 15) * 4];
      T[row][(t & 15) * 4 + 0] = (bf16)(v.x * scale);
      T[row][(t & 15) * 4 + 1] = (bf16)(v.y * scale);
      T[row][(t & 15) * 4 + 2] = (bf16)(v.z * scale);
      T[row][(t & 15) * 4 + 3] = (bf16)(v.w * scale);
    }
    __syncthreads();
    #pragma unroll
    for (int p = 0; p < 4; ++p) {
      int rp = (t >> 4) + p * 16;
      int cb = (t & 15) * 4;
      bf16x4 o = {T[cb + 0][rp], T[cb + 1][rp], T[cb + 2][rp], T[cb + 3][rp]};
      *(bf16x4*)&dst[(size_t)(tc + rp) * HID + tr + cb] = o;
    }
  }
}

// ---------------------------------------------------------------------------
// QKV GEMM: C = Xb[M,K] @ Wt[z][N,K]^T. 128x128 tile, BK=64, global_load_lds
// staging with chunk-rotation swizzle. z=2 writes V transposed (Vt[hid][seq]).
// ---------------------------------------------------------------------------
__global__ __launch_bounds__(256)
void qkv_gemm(const bf16* __restrict__ A, const bf16* __restrict__ Wt,
              bf16* __restrict__ Qg, bf16* __restrict__ Kg,
              bf16* __restrict__ Vt)
{
  __shared__ bf16 sbuf[16384];
  bf16* As = sbuf;
  bf16* Bs = sbuf + 8192;

  const int t = threadIdx.x, lane = t & 63, w = t >> 6;
  const int z = blockIdx.z;
  const int n0 = blockIdx.x * 128, m0 = blockIdx.y * 128;
  const bf16* Bt = Wt + (size_t)z * HID * HID;
  const int wm = (w & 1) * 64, wn = (w >> 1) * 64;
  const int fr = lane & 15, quad = lane >> 4;

  f32x4 acc[4][4] = {};

  const int sr = lane >> 3;              // 0..7
  const int sc = ((lane & 7) - sr) & 7;  // rotated chunk
  const bf16* ga = A  + (size_t)(m0 + w * 32 + sr) * HID + sc * 8;
  const bf16* gb = Bt + (size_t)(n0 + w * 32 + sr) * HID + sc * 8;

  for (int k0 = 0; k0 < HID; k0 += 64) {
    __syncthreads();
    #pragma unroll
    for (int c = 0; c < 4; ++c) {
      gll16(ga + (size_t)(c * 8) * HID + k0, As + (w * 32 + c * 8) * 64);
      gll16(gb + (size_t)(c * 8) * HID + k0, Bs + (w * 32 + c * 8) * 64);
    }
    __syncthreads();
    #pragma unroll
    for (int ks = 0; ks < 2; ++ks) {
      bf16x8 af[4], bg[4];
      #pragma unroll
      for (int i = 0; i < 4; ++i)
        af[i] = *(const bf16x8*)&As[(wm + i * 16 + fr) * 64 +
                                    ((ks * 4 + quad + fr) & 7) * 8];
      #pragma unroll
      for (int i = 0; i < 4; ++i)
        bg[i] = *(const bf16x8*)&Bs[(wn + i * 16 + fr) * 64 +
                                    ((ks * 4 + quad + fr) & 7) * 8];
      #pragma unroll
      for (int mi = 0; mi < 4; ++mi)
        #pragma unroll
        for (int ni = 0; ni < 4; ++ni)
          acc[mi][ni] = __builtin_amdgcn_mfma_f32_16x16x32_bf16(
              af[mi], bg[ni], acc[mi][ni], 0, 0, 0);
    }
  }

  if (z < 2) {
    bf16* C = z ? Kg : Qg;
    #pragma unroll
    for (int mi = 0; mi < 4; ++mi)
      #pragma unroll
      for (int ni = 0; ni < 4; ++ni)
        #pragma unroll
        for (int r = 0; r < 4; ++r)
          C[(size_t)(m0 + wm + mi * 16 + quad * 4 + r) * HID +
            n0 + wn + ni * 16 + fr] = (bf16)acc[mi][ni][r];
  } else {
    __syncthreads();
    // swizzled transpose: col stored at (col + 8*(row&15)) & 127
    #pragma unroll
    for (int mi = 0; mi < 4; ++mi)
      #pragma unroll
      for (int ni = 0; ni < 4; ++ni)
        #pragma unroll
        for (int r = 0; r < 4; ++r) {
          int row = wn + ni * 16 + fr;
          int col = wm + mi * 16 + quad * 4 + r;
          int colS = (col + 8 * (row & 15)) & 127;
          sbuf[row * 128 + colS] = (bf16)acc[mi][ni][r];
        }
    __syncthreads();
    const int row = t >> 1, cb = (t & 1) * 64;
    #pragma unroll
    for (int j = 0; j < 8; ++j) {
      int c0 = (cb + j * 8 + 8 * (row & 15)) & 127;
      *(bf16x8*)&Vt[(size_t)(n0 + row) * SEQ + m0 + cb + j * 8] =
          *(const bf16x8*)&sbuf[row * 128 + c0];
    }
  }
}

// ---------------------------------------------------------------------------
// O-projection: out = Og[M,K] @ Wto[N,K]^T, fp32 out. Same swizzled staging.
// ---------------------------------------------------------------------------
__global__ __launch_bounds__(256)
void oproj_gemm(const bf16* __restrict__ A, const bf16* __restrict__ Bt,
                float* __restrict__ C)
{
  __shared__ bf16 sbuf[16384];
  bf16* As = sbuf;
  bf16* Bs = sbuf + 8192;

  const int t = threadIdx.x, lane = t & 63, w = t >> 6;
  const int n0 = blockIdx.x * 128, m0 = blockIdx.y * 128;
  const int wm = (w & 1) * 64, wn = (w >> 1) * 64;
  const int fr = lane & 15, quad = lane >> 4;

  f32x4 acc[4][4] = {};

  const int sr = lane >> 3;
  const int sc = ((lane & 7) - sr) & 7;
  const bf16* ga = A  + (size_t)(m0 + w * 32 + sr) * HID + sc * 8;
  const bf16* gb = Bt + (size_t)(n0 + w * 32 + sr) * HID + sc * 8;

  for (int k0 = 0; k0 < HID; k0 += 64) {
    __syncthreads();
    #pragma unroll
    for (int c = 0; c < 4; ++c) {
      gll16(ga + (size_t)(c * 8) * HID + k0, As + (w * 32 + c * 8) * 64);
      gll16(gb + (size_t)(c * 8) * HID + k0, Bs + (w * 32 + c * 8) * 64);
    }
    __syncthreads();
    #pragma unroll
    for (int ks = 0; ks < 2; ++ks) {
      bf16x8 af[4], bg[4];
      #pragma unroll
      for (int i = 0; i < 4; ++i)
        af[i] = *(const bf16x8*)&As[(wm + i * 16 + fr) * 64 +
                                    ((ks * 4 + quad + fr) & 7) * 8];
      #pragma unroll
      for (int i = 0; i < 4; ++i)
        bg[i] = *(const bf16x8*)&Bs[(wn + i * 16 + fr) * 64 +
                                    ((ks * 4 + quad + fr) & 7) * 8];
      #pragma unroll
      for (int mi = 0; mi < 4; ++mi)
        #pragma unroll
        for (int ni = 0; ni < 4; ++ni)
          acc[mi][ni] = __builtin_amdgcn_mfma_f32_16x16x32_bf16(
              af[mi], bg[ni], acc[mi][ni], 0, 0, 0);
    }
  }

  #pragma unroll
  for (int mi = 0; mi < 4; ++mi)
    #pragma unroll
    for (int ni = 0; ni < 4; ++ni)
      #pragma unroll
      for (int r = 0; r < 4; ++r)
        C[(size_t)(m0 + wm + mi * 16 + quad * 4 + r) * HID +
          n0 + wn + ni * 16 + fr] = acc[mi][ni][r];
}

// ---------------------------------------------------------------------------
// Attention v15 = attn13 (verified 91.5 us; r14's chain-split spilled and is
// reverted) + s_setprio(1) around the MFMA cluster (T5: zero registers,
// helps when co-resident waves are at different phases -- true here: 4
// independent blocks/CU, no cross-block lockstep).
// ---------------------------------------------------------------------------
__global__ __launch_bounds__(256, 4)
void attn15(const bf16* __restrict__ Q, const bf16* __restrict__ K,
            const bf16* __restrict__ Vt, bf16* __restrict__ Opart,
            float* __restrict__ Den)
{
  __shared__ bf16 Ks[2][4096];
  __shared__ bf16 Vs[2][4096];

  const int t = threadIdx.x, lane = t & 63, w = t >> 6;
  const int h = blockIdx.y, q0 = blockIdx.x * 128, qtr = blockIdx.z;
  const int q = lane & 31, hi = lane >> 5;
  const int qrow = q0 + w * 32 + q;

  // Q B-fragments: bq[j] = Q[qrow][h*64 + j*16 + hi*8 .. +8]
  bf16x8 bq[4];
  #pragma unroll
  for (int j = 0; j < 4; ++j)
    bq[j] = *(const bf16x8*)&Q[(size_t)qrow * HID + h * 64 + j * 16 + hi * 8];

  const bf16 onev = (bf16)1.0f;
  const bf16x8 ones = {onev, onev, onev, onev, onev, onev, onev, onev};

  const int sr = lane >> 3;
  const int sc = ((lane & 7) - sr) & 7;
  const bf16* gk = K  + (size_t)(qtr * 1024 + w * 16 + sr) * HID + h * 64 + sc * 8;
  const bf16* gv = Vt + (size_t)(h * 64 + w * 16 + sr) * SEQ + qtr * 1024 + sc * 8;

  #pragma unroll
  for (int j = 0; j < 2; ++j) {
    gll16(gk + (size_t)(j * 8) * HID, &Ks[0][(w * 16 + j * 8) * 64]);
    gll16(gv + (size_t)(j * 8) * SEQ, &Vs[0][(w * 16 + j * 8) * 64]);
  }

  f32x16 accO[2], accD;
  #pragma unroll
  for (int r = 0; r < 16; ++r) { accO[0][r] = 0.f; accO[1][r] = 0.f; accD[r] = 0.f; }
  float m4[4] = {-3e38f, -3e38f, -3e38f, -3e38f};

  __syncthreads();

  for (int kk = 0; kk < 16; ++kk) {
    const int buf = kk & 1;
    if (kk < 15) {
      const size_t key0n = (size_t)(kk + 1) * 64;
      #pragma unroll
      for (int j = 0; j < 2; ++j) {
        gll16(gk + (key0n + j * 8) * HID, &Ks[buf ^ 1][(w * 16 + j * 8) * 64]);
        gll16(gv + key0n + (size_t)(j * 8) * SEQ,
              &Vs[buf ^ 1][(w * 16 + j * 8) * 64]);
      }
    }

    #pragma unroll
    for (int st = 0; st < 2; ++st) {
      const int r0 = st * 32;         // key sub-tile base row
      // QK^T: 4 chained mfma over d (k=16 each)
      f32x16 s;
      #pragma unroll
      for (int r = 0; r < 16; ++r) s[r] = 0.f;
      __builtin_amdgcn_s_setprio(1);
      #pragma unroll
      for (int j = 0; j < 4; ++j) {
        const int row = r0 + q;
        bf16x8 ak = *(const bf16x8*)&Ks[buf][row * 64 +
                                            ((j * 2 + hi + row) & 7) * 8];
        s = __builtin_amdgcn_mfma_f32_32x32x16_bf16(ak, bq[j], s, 0, 0, 0);
      }
      __builtin_amdgcn_s_setprio(0);

      // running block-max: 3-input max chains (v_max3)
      #pragma unroll
      for (int r = 0; r < 16; r += 4) {
        m4[0] = fmaxf(fmaxf(m4[0], s[r]), s[r + 1]);
        m4[1] = fmaxf(fmaxf(m4[1], s[r + 2]), s[r + 3]);
      }

      // P = exp2(s) directly; den handled by MFMA below
      float p[16];
      #pragma unroll
      for (int r = 0; r < 16; ++r) p[r] = fast_exp2(s[r]);

      unsigned pk[8];
      #pragma unroll
      for (int i = 0; i < 8; ++i) {
        bf16x2 pp = {(bf16)p[2 * i], (bf16)p[2 * i + 1]};
        pk[i] = __builtin_bit_cast(unsigned, pp);
      }
      // half-wave exchange on VALU: post-swap pk[] is the fragment verbatim
      pl32swap(pk[0], pk[2]);
      pl32swap(pk[1], pk[3]);
      pl32swap(pk[4], pk[6]);
      pl32swap(pk[5], pk[7]);
      u32x4 w0 = {pk[0], pk[1], pk[2], pk[3]};
      u32x4 w1 = {pk[4], pk[5], pk[6], pk[7]};
      bf16x8 bp0 = __builtin_bit_cast(bf16x8, w0);
      bf16x8 bp1 = __builtin_bit_cast(bf16x8, w1);

      __builtin_amdgcn_s_setprio(1);
      // den on the MFMA pipe: every row of accD = sum_k P[q][k]
      accD = __builtin_amdgcn_mfma_f32_32x32x16_bf16(ones, bp0, accD, 0, 0, 0);
      accD = __builtin_amdgcn_mfma_f32_32x32x16_bf16(ones, bp1, accD, 0, 0, 0);

      // PV: O^T[db] += V^T . P^T  (k = keys, 2 chunks of 16)
      #pragma unroll
      for (int db = 0; db < 2; ++db) {
        const int rowd = db * 32 + q;
        bf16x8 av0 = *(const bf16x8*)&Vs[buf][rowd * 64 +
                       ((st * 4 + 0 + hi + rowd) & 7) * 8];
        accO[db] = __builtin_amdgcn_mfma_f32_32x32x16_bf16(av0, bp0, accO[db], 0, 0, 0);
        bf16x8 av1 = *(const bf16x8*)&Vs[buf][rowd * 64 +
                       ((st * 4 + 2 + hi + rowd) & 7) * 8];
        accO[db] = __builtin_amdgcn_mfma_f32_32x32x16_bf16(av1, bp1, accO[db], 0, 0, 0);
      }
      __builtin_amdgcn_s_setprio(0);
    }
    __syncthreads();
  }

  // epilogue: merge block max, lane-major locally-normalized partial + den
  {
    const float l = accD[0];
    float m_true = fmaxf(fmaxf(m4[0], m4[1]), fmaxf(m4[2], m4[3]));
    m_true = fmaxf(m_true, __shfl_xor(m_true, 32));
    const float inv = 1.0f / l;
    const size_t base =
        ((size_t)(qtr * 16 + h) * 128 + (q0 >> 5) + w) * 2048 + (size_t)lane * 32;
    #pragma unroll
    for (int j = 0; j < 4; ++j) {
      bf16x8 wv;
      #pragma unroll
      for (int e = 0; e < 8; ++e)
        wv[e] = (bf16)(accO[j >> 1][(j & 1) * 8 + e] * inv);
      *(bf16x8*)&Opart[base + j * 8] = wv;
    }
    if (hi == 0)
      Den[(size_t)(qtr * 16 + h) * SEQ + qrow] = l * fast_exp2(-m_true);
  }
}

// ---------------------------------------------------------------------------
// Combine8: one wave per (h, 32-query seg). Reads 4 lane-major partials
// (coalesced), weights by den_rb / sum(den), LDS-transposes reg layout
// (d = db*32 + (r&3) + 8*(r>>2) + 4*hi) to [q][d], writes Og coalesced.
// ---------------------------------------------------------------------------
__global__ __launch_bounds__(64)
void combine8(const bf16* __restrict__ Opart, const float* __restrict__ Den,
              bf16* __restrict__ Og)
{
  __shared__ bf16 T[32][72];
  const int lane = threadIdx.x & 63;
  const int h = blockIdx.y, qs = blockIdx.x;   // qs in [0,128)
  const int q = lane & 31, hi = lane >> 5;

  float dw[4];
  #pragma unroll
  for (int rb = 0; rb < 4; ++rb)
    dw[rb] = Den[(size_t)(rb * 16 + h) * SEQ + qs * 32 + q];
  const float inv = 1.0f / (dw[0] + dw[1] + dw[2] + dw[3]);

  float acc[32];
  #pragma unroll
  for (int i = 0; i < 32; ++i) acc[i] = 0.f;
  #pragma unroll
  for (int rb = 0; rb < 4; ++rb) {
    const float wq = dw[rb] * inv;
    const size_t base =
        ((size_t)(rb * 16 + h) * 128 + qs) * 2048 + (size_t)lane * 32;
    #pragma unroll
    for (int j = 0; j < 4; ++j) {
      bf16x8 v = *(const bf16x8*)&Opart[base + j * 8];
      #pragma unroll
      for (int e = 0; e < 8; ++e) acc[j * 8 + e] += wq * (float)v[e];
    }
  }

  #pragma unroll
  for (int idx = 0; idx < 32; ++idx) {
    const int db = idx >> 4, r = idx & 15;
    const int d = db * 32 + (r & 3) + 8 * (r >> 2) + 4 * hi;
    T[q][d] = (bf16)acc[idx];
  }
  __syncthreads();
  #pragma unroll
  for (int p = 0; p < 4; ++p) {
    const int row = p * 8 + (lane >> 3);
    *(bf16x8*)&Og[(size_t)(qs * 32 + row) * HID + h * 64 + (lane & 7) * 8] =
        *(const bf16x8*)&T[row][(lane & 7) * 8];
  }
}

// ---------------------------------------------------------------------------
// Attention v5 (fallback if workspace < 81 MB): round-3-verified.
// ---------------------------------------------------------------------------
#define THR_L2 12.0f

__global__ __launch_bounds__(256, 2)
void attn5(const bf16* __restrict__ Q, const bf16* __restrict__ K,
           const bf16* __restrict__ Vt, bf16* __restrict__ O)
{
  __shared__ bf16 Ks[2][4096];
  __shared__ bf16 Vs[2][4096];
  __shared__ bf16 Ps[4][1024];

  const int t = threadIdx.x, lane = t & 63, w = t >> 6;
  const int h = blockIdx.y, q0 = blockIdx.x * 128;
  const int fr = lane & 15, quad = lane >> 4;

  bf16x8 bq[2][2];
  #pragma unroll
  for (int qf = 0; qf < 2; ++qf)
    #pragma unroll
    for (int ks = 0; ks < 2; ++ks)
      bq[qf][ks] = *(const bf16x8*)&Q[(size_t)(q0 + w * 32 + qf * 16 + fr) * HID
                                      + h * 64 + ks * 32 + quad * 8];

  const int sr = lane >> 3;
  const int sc = ((lane & 7) - sr) & 7;
  const bf16* gk = K  + (size_t)(w * 16 + sr) * HID + h * 64 + sc * 8;
  const bf16* gv = Vt + (size_t)(h * 64 + w * 16 + sr) * SEQ + sc * 8;

  #pragma unroll
  for (int j = 0; j < 2; ++j) {
    gll16(gk + (size_t)(j * 8) * HID, &Ks[0][(w * 16 + j * 8) * 64]);
    gll16(gv + (size_t)(j * 8) * SEQ, &Vs[0][(w * 16 + j * 8) * 64]);
  }

  f32x4 accN[2][4] = {};
  f32x4 accO[2][4] = {};
  float m_used[2] = {-3e38f, -3e38f}, m_true[2] = {-3e38f, -3e38f};
  float l_i[2] = {0.f, 0.f}, den[2] = {0.f, 0.f};

  __syncthreads();

  for (int kk = 0; kk < 64; ++kk) {
    const int buf = kk & 1;
    if (kk < 63) {
      const size_t key0n = (size_t)(kk + 1) * 64;
      #pragma unroll
      for (int j = 0; j < 2; ++j) {
        gll16(gk + (key0n + j * 8) * HID, &Ks[buf ^ 1][(w * 16 + j * 8) * 64]);
        gll16(gv + key0n + (size_t)(j * 8) * SEQ,
              &Vs[buf ^ 1][(w * 16 + j * 8) * 64]);
      }
    }

    bf16x8 ak[4][2];
    #pragma unroll
    for (int mt = 0; mt < 4; ++mt)
      #pragma unroll
      for (int ks = 0; ks < 2; ++ks)
        ak[mt][ks] = *(const bf16x8*)&Ks[buf][(mt * 16 + fr) * 64 +
                                             ((ks * 4 + quad + fr) & 7) * 8];

    f32x4 s[2][4];
    #pragma unroll
    for (int qf = 0; qf < 2; ++qf)
      #pragma unroll
      for (int mt = 0; mt < 4; ++mt) {
        f32x4 z = {};
        z = __builtin_amdgcn_mfma_f32_16x16x32_bf16(ak[mt][0], bq[qf][0], z, 0, 0, 0);
        z = __builtin_amdgcn_mfma_f32_16x16x32_bf16(ak[mt][1], bq[qf][1], z, 0, 0, 0);
        s[qf][mt] = z;
      }

    bf16x8 bp[2][2];
    #pragma unroll
    for (int qf = 0; qf < 2; ++qf) {
      float mx0 = fmaxf(fmaxf(s[qf][0][0], s[qf][0][1]), fmaxf(s[qf][0][2], s[qf][0][3]));
      float mx1 = fmaxf(fmaxf(s[qf][1][0], s[qf][1][1]), fmaxf(s[qf][1][2], s[qf][1][3]));
      float mx2 = fmaxf(fmaxf(s[qf][2][0], s[qf][2][1]), fmaxf(s[qf][2][2], s[qf][2][3]));
      float mx3 = fmaxf(fmaxf(s[qf][3][0], s[qf][3][1]), fmaxf(s[qf][3][2], s[qf][3][3]));
      float mx = fmaxf(fmaxf(mx0, mx1), fmaxf(mx2, mx3));
      mx = fmaxf(mx, __shfl_xor(mx, 16));
      mx = fmaxf(mx, __shfl_xor(mx, 32));
      m_true[qf] = fmaxf(m_true[qf], mx);

      if (__any(mx > m_used[qf] + THR_L2)) {
        const float mn = fmaxf(m_used[qf], mx);
        const float a = fast_exp2(m_used[qf] - mn);
        m_used[qf] = mn;
        l_i[qf] *= a;
        #pragma unroll
        for (int dt = 0; dt < 4; ++dt) accO[qf][dt] *= a;
      }

      float sum = 0.f;
      const int prow = fr * 64;
      #pragma unroll
      for (int mt = 0; mt < 4; ++mt) {
        float p0 = fast_exp2(s[qf][mt][0] - m_used[qf]);
        float p1 = fast_exp2(s[qf][mt][1] - m_used[qf]);
        float p2 = fast_exp2(s[qf][mt][2] - m_used[qf]);
        float p3 = fast_exp2(s[qf][mt][3] - m_used[qf]);
        sum += (p0 + p1) + (p2 + p3);
        bf16x4 pv = {(bf16)p0, (bf16)p1, (bf16)p2, (bf16)p3};
        *(bf16x4*)&Ps[w][prow + ((mt * 2 + (quad >> 1) + fr) & 7) * 8 +
                         (quad & 1) * 4] = pv;
      }
      sum += __shfl_xor(sum, 16);
      sum += __shfl_xor(sum, 32);
      l_i[qf] += sum;

      #pragma unroll
      for (int ks = 0; ks < 2; ++ks)
        bp[qf][ks] = *(const bf16x8*)&Ps[w][fr * 64 +
                                            ((ks * 4 + quad + fr) & 7) * 8];
    }

    #pragma unroll
    for (int ks = 0; ks < 2; ++ks)
      #pragma unroll
      for (int dt = 0; dt < 4; ++dt) {
        bf16x8 av = *(const bf16x8*)&Vs[buf][(dt * 16 + fr) * 64 +
                                            ((ks * 4 + quad + fr) & 7) * 8];
        accO[0][dt] = __builtin_amdgcn_mfma_f32_16x16x32_bf16(av, bp[0][ks], accO[0][dt], 0, 0, 0);
        accO[1][dt] = __builtin_amdgcn_mfma_f32_16x16x32_bf16(av, bp[1][ks], accO[1][dt], 0, 0, 0);
      }

    if ((kk & 15) == 15) {
      #pragma unroll
      for (int qf = 0; qf < 2; ++qf) {
        const float c = fast_exp2(m_used[qf] - m_true[qf]);
        den[qf] += l_i[qf] * c;
        #pragma unroll
        for (int dt = 0; dt < 4; ++dt)
          #pragma unroll
          for (int r = 0; r < 4; ++r) accN[qf][dt][r] += accO[qf][dt][r] * c;
        #pragma unroll
        for (int dt = 0; dt < 4; ++dt) accO[qf][dt] = (f32x4){0.f, 0.f, 0.f, 0.f};
        l_i[qf] = 0.f; m_used[qf] = -3e38f; m_true[qf] = -3e38f;
      }
    }
    __syncthreads();
  }

  #pragma unroll
  for (int qf = 0; qf < 2; ++qf) {
    const float inv = 1.0f / den[qf];
    const size_t orow = (size_t)(q0 + w * 32 + qf * 16 + fr) * HID + h * 64;
    #pragma unroll
    for (int dt = 0; dt < 4; ++dt) {
      bf16x4 ov = {(bf16)(accN[qf][dt][0] * inv), (bf16)(accN[qf][dt][1] * inv),
                   (bf16)(accN[qf][dt][2] * inv), (bf16)(accN[qf][dt][3] * inv)};
      *(bf16x4*)&O[orow + dt * 16 + quad * 4] = ov;
    }
  }
}

extern "C" void kernel_launch(void* const* d_in, const int* in_sizes, int n_in,
                              void* d_out, int out_size, void* d_ws, size_t ws_size,
                              hipStream_t stream)
{
  const float* X  = (const float*)d_in[0];
  const float* Wq = (const float*)d_in[1];
  const float* Wk = (const float*)d_in[2];
  const float* Wv = (const float*)d_in[3];
  const float* Wo = (const float*)d_in[4];
  float* out = (float*)d_out;

  const size_t MB = 1024 * 1024;
  bf16*  Xb  = (bf16*)d_ws;                       // 8 MB
  bf16*  Wt  = (bf16*)((char*)d_ws + 8  * MB);    // 4 x 2 MB
  bf16*  Qg  = (bf16*)((char*)d_ws + 16 * MB);    // 8 MB
  bf16*  Kg  = (bf16*)((char*)d_ws + 24 * MB);    // 8 MB
  bf16*  Vtg = (bf16*)((char*)d_ws + 32 * MB);    // 8 MB, [hid][seq]
  bf16*  Og  = (bf16*)((char*)d_ws + 40 * MB);    // 8 MB
  bf16*  Opart = (bf16*)((char*)d_ws + 48 * MB);  // 32 MB lane-major partials
  float* Den   = (float*)((char*)d_ws + 80 * MB); // 1 MB fp32

  prep_kernel<<<dim3(256, 1, 5), 256, 0, stream>>>(X, Wq, Wk, Wv, Wo, Xb, Wt);
  qkv_gemm<<<dim3(HID / 128, SEQ / 128, 3), 256, 0, stream>>>(Xb, Wt, Qg, Kg, Vtg);
  if (ws_size >= 81 * MB) {
    attn15<<<dim3(SEQ / 128, NHEADS, 4), 256, 0, stream>>>(Qg, Kg, Vtg, Opart, Den);
    combine8<<<dim3(SEQ / 32, NHEADS), 64, 0, stream>>>(Opart, Den, Og);
  } else {
    attn5<<<dim3(SEQ / 128, NHEADS), 256, 0, stream>>>(Qg, Kg, Vtg, Og);
  }
  oproj_gemm<<<dim3(HID / 128, SEQ / 128), 256, 0, stream>>>(
      Og, Wt + (size_t)3 * HID * HID, out);
}

// Round 16
// 235.512 us; speedup vs baseline: 2.3566x; 1.0074x over previous
//
#include <hip/hip_runtime.h>
#include <hip/hip_bf16.h>

typedef __bf16 bf16;
typedef bf16 bf16x2 __attribute__((ext_vector_type(2)));
typedef bf16 bf16x4 __attribute__((ext_vector_type(4)));
typedef bf16 bf16x8 __attribute__((ext_vector_type(8)));
typedef float f32x4 __attribute__((ext_vector_type(4)));
typedef float f32x16 __attribute__((ext_vector_type(16)));
typedef unsigned int u32x4 __attribute__((ext_vector_type(4)));

#define HID 1024
#define NHEADS 16
#define HD 64
#define SEQ 4096

__device__ __forceinline__ void gll16(const void* g, void* l) {
  __builtin_amdgcn_global_load_lds(
      (const __attribute__((address_space(1))) void*)g,
      (__attribute__((address_space(3))) void*)l, 16, 0, 0);
}

__device__ __forceinline__ float fast_exp2(float x) {
#if __has_builtin(__builtin_amdgcn_exp2f)
  return __builtin_amdgcn_exp2f(x);
#else
  return __expf(x * 0.6931471805599453f);
#endif
}

// gfx950 half-wave swap: X' = [X.lo | Y.lo], Y' = [X.hi | Y.hi]
__device__ __forceinline__ void pl32swap(unsigned& a, unsigned& b) {
  asm volatile("v_permlane32_swap_b32 %0, %1" : "+v"(a), "+v"(b));
}

// ---------------------------------------------------------------------------
// Prep: z=0 convert X fp32->bf16; z=1..4 transpose+convert W -> Wt[out][in].
// Attention scale folded into Wq in LOG2 domain: 0.125 * log2(e).
// ---------------------------------------------------------------------------
__global__ __launch_bounds__(256)
void prep_kernel(const float* __restrict__ X,
                 const float* __restrict__ Wq, const float* __restrict__ Wk,
                 const float* __restrict__ Wv, const float* __restrict__ Wo,
                 bf16* __restrict__ Xb, bf16* __restrict__ Wt)
{
  const int z = blockIdx.z, t = threadIdx.x, bx = blockIdx.x;
  if (z == 0) {
    const float4* src = (const float4*)X;
    const int gid = bx * 256 + t;
    #pragma unroll
    for (int i = 0; i < 16; ++i) {
      float4 v = src[gid + i * 65536];
      bf16x4 o = {(bf16)v.x, (bf16)v.y, (bf16)v.z, (bf16)v.w};
      *(bf16x4*)&Xb[(size_t)(gid + i * 65536) * 4] = o;
    }
  } else {
    const float* W = (z == 1) ? Wq : (z == 2) ? Wk : (z == 3) ? Wv : Wo;
    bf16* dst = Wt + (size_t)(z - 1) * HID * HID;
    const float scale = (z == 1) ? 0.18033688011112042f : 1.0f;  // 0.125*log2(e)
    __shared__ bf16 T[64][68];
    const int tr = (bx >> 4) * 64, tc = (bx & 15) * 64;
    #pragma unroll
    for (int p = 0; p < 4; ++p) {
      int row = (t >> 4) + p * 16;
      float4 v = *(const float4*)&W[(size_t)(tr + row) * HID + tc + (t & 15) * 4];
      T[row][(t & 15) * 4 + 0] = (bf16)(v.x * scale);
      T[row][(t & 15) * 4 + 1] = (bf16)(v.y * scale);
      T[row][(t & 15) * 4 + 2] = (bf16)(v.z * scale);
      T[row][(t & 15) * 4 + 3] = (bf16)(v.w * scale);
    }
    __syncthreads();
    #pragma unroll
    for (int p = 0; p < 4; ++p) {
      int rp = (t >> 4) + p * 16;
      int cb = (t & 15) * 4;
      bf16x4 o = {T[cb + 0][rp], T[cb + 1][rp], T[cb + 2][rp], T[cb + 3][rp]};
      *(bf16x4*)&dst[(size_t)(tc + rp) * HID + tr + cb] = o;
    }
  }
}

// ---------------------------------------------------------------------------
// QKV GEMM: C = Xb[M,K] @ Wt[z][N,K]^T. 128x128 tile, BK=64, global_load_lds
// staging with chunk-rotation swizzle. z=2 writes V transposed (Vt[hid][seq]).
// ---------------------------------------------------------------------------
__global__ __launch_bounds__(256)
void qkv_gemm(const bf16* __restrict__ A, const bf16* __restrict__ Wt,
              bf16* __restrict__ Qg, bf16* __restrict__ Kg,
              bf16* __restrict__ Vt)
{
  __shared__ bf16 sbuf[16384];
  bf16* As = sbuf;
  bf16* Bs = sbuf + 8192;

  const int t = threadIdx.x, lane = t & 63, w = t >> 6;
  const int z = blockIdx.z;
  const int n0 = blockIdx.x * 128, m0 = blockIdx.y * 128;
  const bf16* Bt = Wt + (size_t)z * HID * HID;
  const int wm = (w & 1) * 64, wn = (w >> 1) * 64;
  const int fr = lane & 15, quad = lane >> 4;

  f32x4 acc[4][4] = {};

  const int sr = lane >> 3;              // 0..7
  const int sc = ((lane & 7) - sr) & 7;  // rotated chunk
  const bf16* ga = A  + (size_t)(m0 + w * 32 + sr) * HID + sc * 8;
  const bf16* gb = Bt + (size_t)(n0 + w * 32 + sr) * HID + sc * 8;

  for (int k0 = 0; k0 < HID; k0 += 64) {
    __syncthreads();
    #pragma unroll
    for (int c = 0; c < 4; ++c) {
      gll16(ga + (size_t)(c * 8) * HID + k0, As + (w * 32 + c * 8) * 64);
      gll16(gb + (size_t)(c * 8) * HID + k0, Bs + (w * 32 + c * 8) * 64);
    }
    __syncthreads();
    #pragma unroll
    for (int ks = 0; ks < 2; ++ks) {
      bf16x8 af[4], bg[4];
      #pragma unroll
      for (int i = 0; i < 4; ++i)
        af[i] = *(const bf16x8*)&As[(wm + i * 16 + fr) * 64 +
                                    ((ks * 4 + quad + fr) & 7) * 8];
      #pragma unroll
      for (int i = 0; i < 4; ++i)
        bg[i] = *(const bf16x8*)&Bs[(wn + i * 16 + fr) * 64 +
                                    ((ks * 4 + quad + fr) & 7) * 8];
      #pragma unroll
      for (int mi = 0; mi < 4; ++mi)
        #pragma unroll
        for (int ni = 0; ni < 4; ++ni)
          acc[mi][ni] = __builtin_amdgcn_mfma_f32_16x16x32_bf16(
              af[mi], bg[ni], acc[mi][ni], 0, 0, 0);
    }
  }

  if (z < 2) {
    bf16* C = z ? Kg : Qg;
    #pragma unroll
    for (int mi = 0; mi < 4; ++mi)
      #pragma unroll
      for (int ni = 0; ni < 4; ++ni)
        #pragma unroll
        for (int r = 0; r < 4; ++r)
          C[(size_t)(m0 + wm + mi * 16 + quad * 4 + r) * HID +
            n0 + wn + ni * 16 + fr] = (bf16)acc[mi][ni][r];
  } else {
    __syncthreads();
    // swizzled transpose: col stored at (col + 8*(row&15)) & 127
    #pragma unroll
    for (int mi = 0; mi < 4; ++mi)
      #pragma unroll
      for (int ni = 0; ni < 4; ++ni)
        #pragma unroll
        for (int r = 0; r < 4; ++r) {
          int row = wn + ni * 16 + fr;
          int col = wm + mi * 16 + quad * 4 + r;
          int colS = (col + 8 * (row & 15)) & 127;
          sbuf[row * 128 + colS] = (bf16)acc[mi][ni][r];
        }
    __syncthreads();
    const int row = t >> 1, cb = (t & 1) * 64;
    #pragma unroll
    for (int j = 0; j < 8; ++j) {
      int c0 = (cb + j * 8 + 8 * (row & 15)) & 127;
      *(bf16x8*)&Vt[(size_t)(n0 + row) * SEQ + m0 + cb + j * 8] =
          *(const bf16x8*)&sbuf[row * 128 + c0];
    }
  }
}

// ---------------------------------------------------------------------------
// O-projection v2: out = Og[M,K] @ Wto[N,K]^T, fp32 out. 64x128 tile
// (M-split): grid (8,64) = 512 blocks = 2 blocks/CU (was 256 = 1/CU with
// zero barrier-stall overlap). Waves 2x2: each computes 32x64 (acc[2][4]).
// A-tile 64x64 (2 chunks/wave), B-tile 128x64 (4 chunks/wave), LDS 24 KB.
// Same row-mod-8 chunk-rotation swizzle (staged row = base+c*8+sr keeps
// row&7 = sr, so the rotation key transfers verbatim).
// ---------------------------------------------------------------------------
__global__ __launch_bounds__(256)
void oproj_gemm(const bf16* __restrict__ A, const bf16* __restrict__ Bt,
                float* __restrict__ C)
{
  __shared__ bf16 sbuf[12288];
  bf16* As = sbuf;           // 64 x 64
  bf16* Bs = sbuf + 4096;    // 128 x 64

  const int t = threadIdx.x, lane = t & 63, w = t >> 6;
  const int n0 = blockIdx.x * 128, m0 = blockIdx.y * 64;
  const int wm = (w & 1) * 32, wn = (w >> 1) * 64;
  const int fr = lane & 15, quad = lane >> 4;

  f32x4 acc[2][4] = {};

  const int sr = lane >> 3;
  const int sc = ((lane & 7) - sr) & 7;
  const bf16* ga = A  + (size_t)(m0 + w * 16 + sr) * HID + sc * 8;
  const bf16* gb = Bt + (size_t)(n0 + w * 32 + sr) * HID + sc * 8;

  for (int k0 = 0; k0 < HID; k0 += 64) {
    __syncthreads();
    #pragma unroll
    for (int c = 0; c < 2; ++c)
      gll16(ga + (size_t)(c * 8) * HID + k0, As + (w * 16 + c * 8) * 64);
    #pragma unroll
    for (int c = 0; c < 4; ++c)
      gll16(gb + (size_t)(c * 8) * HID + k0, Bs + (w * 32 + c * 8) * 64);
    __syncthreads();
    #pragma unroll
    for (int ks = 0; ks < 2; ++ks) {
      bf16x8 af[2], bg[4];
      #pragma unroll
      for (int i = 0; i < 2; ++i)
        af[i] = *(const bf16x8*)&As[(wm + i * 16 + fr) * 64 +
                                    ((ks * 4 + quad + fr) & 7) * 8];
      #pragma unroll
      for (int i = 0; i < 4; ++i)
        bg[i] = *(const bf16x8*)&Bs[(wn + i * 16 + fr) * 64 +
                                    ((ks * 4 + quad + fr) & 7) * 8];
      #pragma unroll
      for (int mi = 0; mi < 2; ++mi)
        #pragma unroll
        for (int ni = 0; ni < 4; ++ni)
          acc[mi][ni] = __builtin_amdgcn_mfma_f32_16x16x32_bf16(
              af[mi], bg[ni], acc[mi][ni], 0, 0, 0);
    }
  }

  #pragma unroll
  for (int mi = 0; mi < 2; ++mi)
    #pragma unroll
    for (int ni = 0; ni < 4; ++ni)
      #pragma unroll
      for (int r = 0; r < 4; ++r)
        C[(size_t)(m0 + wm + mi * 16 + quad * 4 + r) * HID +
          n0 + wn + ni * 16 + fr] = acc[mi][ni][r];
}

// ---------------------------------------------------------------------------
// Attention v15 (verified 88.7 us): 32x32 structure, exp2-direct softmax,
// den-on-MFMA, permlane32 exchange, setprio around MFMA clusters.
// ---------------------------------------------------------------------------
__global__ __launch_bounds__(256, 4)
void attn15(const bf16* __restrict__ Q, const bf16* __restrict__ K,
            const bf16* __restrict__ Vt, bf16* __restrict__ Opart,
            float* __restrict__ Den)
{
  __shared__ bf16 Ks[2][4096];
  __shared__ bf16 Vs[2][4096];

  const int t = threadIdx.x, lane = t & 63, w = t >> 6;
  const int h = blockIdx.y, q0 = blockIdx.x * 128, qtr = blockIdx.z;
  const int q = lane & 31, hi = lane >> 5;
  const int qrow = q0 + w * 32 + q;

  // Q B-fragments: bq[j] = Q[qrow][h*64 + j*16 + hi*8 .. +8]
  bf16x8 bq[4];
  #pragma unroll
  for (int j = 0; j < 4; ++j)
    bq[j] = *(const bf16x8*)&Q[(size_t)qrow * HID + h * 64 + j * 16 + hi * 8];

  const bf16 onev = (bf16)1.0f;
  const bf16x8 ones = {onev, onev, onev, onev, onev, onev, onev, onev};

  const int sr = lane >> 3;
  const int sc = ((lane & 7) - sr) & 7;
  const bf16* gk = K  + (size_t)(qtr * 1024 + w * 16 + sr) * HID + h * 64 + sc * 8;
  const bf16* gv = Vt + (size_t)(h * 64 + w * 16 + sr) * SEQ + qtr * 1024 + sc * 8;

  #pragma unroll
  for (int j = 0; j < 2; ++j) {
    gll16(gk + (size_t)(j * 8) * HID, &Ks[0][(w * 16 + j * 8) * 64]);
    gll16(gv + (size_t)(j * 8) * SEQ, &Vs[0][(w * 16 + j * 8) * 64]);
  }

  f32x16 accO[2], accD;
  #pragma unroll
  for (int r = 0; r < 16; ++r) { accO[0][r] = 0.f; accO[1][r] = 0.f; accD[r] = 0.f; }
  float m4[4] = {-3e38f, -3e38f, -3e38f, -3e38f};

  __syncthreads();

  for (int kk = 0; kk < 16; ++kk) {
    const int buf = kk & 1;
    if (kk < 15) {
      const size_t key0n = (size_t)(kk + 1) * 64;
      #pragma unroll
      for (int j = 0; j < 2; ++j) {
        gll16(gk + (key0n + j * 8) * HID, &Ks[buf ^ 1][(w * 16 + j * 8) * 64]);
        gll16(gv + key0n + (size_t)(j * 8) * SEQ,
              &Vs[buf ^ 1][(w * 16 + j * 8) * 64]);
      }
    }

    #pragma unroll
    for (int st = 0; st < 2; ++st) {
      const int r0 = st * 32;         // key sub-tile base row
      // QK^T: 4 chained mfma over d (k=16 each)
      f32x16 s;
      #pragma unroll
      for (int r = 0; r < 16; ++r) s[r] = 0.f;
      __builtin_amdgcn_s_setprio(1);
      #pragma unroll
      for (int j = 0; j < 4; ++j) {
        const int row = r0 + q;
        bf16x8 ak = *(const bf16x8*)&Ks[buf][row * 64 +
                                            ((j * 2 + hi + row) & 7) * 8];
        s = __builtin_amdgcn_mfma_f32_32x32x16_bf16(ak, bq[j], s, 0, 0, 0);
      }
      __builtin_amdgcn_s_setprio(0);

      // running block-max: 3-input max chains (v_max3)
      #pragma unroll
      for (int r = 0; r < 16; r += 4) {
        m4[0] = fmaxf(fmaxf(m4[0], s[r]), s[r + 1]);
        m4[1] = fmaxf(fmaxf(m4[1], s[r + 2]), s[r + 3]);
      }

      // P = exp2(s) directly; den handled by MFMA below
      float p[16];
      #pragma unroll
      for (int r = 0; r < 16; ++r) p[r] = fast_exp2(s[r]);

      unsigned pk[8];
      #pragma unroll
      for (int i = 0; i < 8; ++i) {
        bf16x2 pp = {(bf16)p[2 * i], (bf16)p[2 * i + 1]};
        pk[i] = __builtin_bit_cast(unsigned, pp);
      }
      // half-wave exchange on VALU: post-swap pk[] is the fragment verbatim
      pl32swap(pk[0], pk[2]);
      pl32swap(pk[1], pk[3]);
      pl32swap(pk[4], pk[6]);
      pl32swap(pk[5], pk[7]);
      u32x4 w0 = {pk[0], pk[1], pk[2], pk[3]};
      u32x4 w1 = {pk[4], pk[5], pk[6], pk[7]};
      bf16x8 bp0 = __builtin_bit_cast(bf16x8, w0);
      bf16x8 bp1 = __builtin_bit_cast(bf16x8, w1);

      __builtin_amdgcn_s_setprio(1);
      // den on the MFMA pipe: every row of accD = sum_k P[q][k]
      accD = __builtin_amdgcn_mfma_f32_32x32x16_bf16(ones, bp0, accD, 0, 0, 0);
      accD = __builtin_amdgcn_mfma_f32_32x32x16_bf16(ones, bp1, accD, 0, 0, 0);

      // PV: O^T[db] += V^T . P^T  (k = keys, 2 chunks of 16)
      #pragma unroll
      for (int db = 0; db < 2; ++db) {
        const int rowd = db * 32 + q;
        bf16x8 av0 = *(const bf16x8*)&Vs[buf][rowd * 64 +
                       ((st * 4 + 0 + hi + rowd) & 7) * 8];
        accO[db] = __builtin_amdgcn_mfma_f32_32x32x16_bf16(av0, bp0, accO[db], 0, 0, 0);
        bf16x8 av1 = *(const bf16x8*)&Vs[buf][rowd * 64 +
                       ((st * 4 + 2 + hi + rowd) & 7) * 8];
        accO[db] = __builtin_amdgcn_mfma_f32_32x32x16_bf16(av1, bp1, accO[db], 0, 0, 0);
      }
      __builtin_amdgcn_s_setprio(0);
    }
    __syncthreads();
  }

  // epilogue: merge block max, lane-major locally-normalized partial + den
  {
    const float l = accD[0];
    float m_true = fmaxf(fmaxf(m4[0], m4[1]), fmaxf(m4[2], m4[3]));
    m_true = fmaxf(m_true, __shfl_xor(m_true, 32));
    const float inv = 1.0f / l;
    const size_t base =
        ((size_t)(qtr * 16 + h) * 128 + (q0 >> 5) + w) * 2048 + (size_t)lane * 32;
    #pragma unroll
    for (int j = 0; j < 4; ++j) {
      bf16x8 wv;
      #pragma unroll
      for (int e = 0; e < 8; ++e)
        wv[e] = (bf16)(accO[j >> 1][(j & 1) * 8 + e] * inv);
      *(bf16x8*)&Opart[base + j * 8] = wv;
    }
    if (hi == 0)
      Den[(size_t)(qtr * 16 + h) * SEQ + qrow] = l * fast_exp2(-m_true);
  }
}

// ---------------------------------------------------------------------------
// Combine8: one wave per (h, 32-query seg). Reads 4 lane-major partials
// (coalesced), weights by den_rb / sum(den), LDS-transposes reg layout
// (d = db*32 + (r&3) + 8*(r>>2) + 4*hi) to [q][d], writes Og coalesced.
// ---------------------------------------------------------------------------
__global__ __launch_bounds__(64)
void combine8(const bf16* __restrict__ Opart, const float* __restrict__ Den,
              bf16* __restrict__ Og)
{
  __shared__ bf16 T[32][72];
  const int lane = threadIdx.x & 63;
  const int h = blockIdx.y, qs = blockIdx.x;   // qs in [0,128)
  const int q = lane & 31, hi = lane >> 5;

  float dw[4];
  #pragma unroll
  for (int rb = 0; rb < 4; ++rb)
    dw[rb] = Den[(size_t)(rb * 16 + h) * SEQ + qs * 32 + q];
  const float inv = 1.0f / (dw[0] + dw[1] + dw[2] + dw[3]);

  float acc[32];
  #pragma unroll
  for (int i = 0; i < 32; ++i) acc[i] = 0.f;
  #pragma unroll
  for (int rb = 0; rb < 4; ++rb) {
    const float wq = dw[rb] * inv;
    const size_t base =
        ((size_t)(rb * 16 + h) * 128 + qs) * 2048 + (size_t)lane * 32;
    #pragma unroll
    for (int j = 0; j < 4; ++j) {
      bf16x8 v = *(const bf16x8*)&Opart[base + j * 8];
      #pragma unroll
      for (int e = 0; e < 8; ++e) acc[j * 8 + e] += wq * (float)v[e];
    }
  }

  #pragma unroll
  for (int idx = 0; idx < 32; ++idx) {
    const int db = idx >> 4, r = idx & 15;
    const int d = db * 32 + (r & 3) + 8 * (r >> 2) + 4 * hi;
    T[q][d] = (bf16)acc[idx];
  }
  __syncthreads();
  #pragma unroll
  for (int p = 0; p < 4; ++p) {
    const int row = p * 8 + (lane >> 3);
    *(bf16x8*)&Og[(size_t)(qs * 32 + row) * HID + h * 64 + (lane & 7) * 8] =
        *(const bf16x8*)&T[row][(lane & 7) * 8];
  }
}

// ---------------------------------------------------------------------------
// Attention v5 (fallback if workspace < 81 MB): round-3-verified.
// ---------------------------------------------------------------------------
#define THR_L2 12.0f

__global__ __launch_bounds__(256, 2)
void attn5(const bf16* __restrict__ Q, const bf16* __restrict__ K,
           const bf16* __restrict__ Vt, bf16* __restrict__ O)
{
  __shared__ bf16 Ks[2][4096];
  __shared__ bf16 Vs[2][4096];
  __shared__ bf16 Ps[4][1024];

  const int t = threadIdx.x, lane = t & 63, w = t >> 6;
  const int h = blockIdx.y, q0 = blockIdx.x * 128;
  const int fr = lane & 15, quad = lane >> 4;

  bf16x8 bq[2][2];
  #pragma unroll
  for (int qf = 0; qf < 2; ++qf)
    #pragma unroll
    for (int ks = 0; ks < 2; ++ks)
      bq[qf][ks] = *(const bf16x8*)&Q[(size_t)(q0 + w * 32 + qf * 16 + fr) * HID
                                      + h * 64 + ks * 32 + quad * 8];

  const int sr = lane >> 3;
  const int sc = ((lane & 7) - sr) & 7;
  const bf16* gk = K  + (size_t)(w * 16 + sr) * HID + h * 64 + sc * 8;
  const bf16* gv = Vt + (size_t)(h * 64 + w * 16 + sr) * SEQ + sc * 8;

  #pragma unroll
  for (int j = 0; j < 2; ++j) {
    gll16(gk + (size_t)(j * 8) * HID, &Ks[0][(w * 16 + j * 8) * 64]);
    gll16(gv + (size_t)(j * 8) * SEQ, &Vs[0][(w * 16 + j * 8) * 64]);
  }

  f32x4 accN[2][4] = {};
  f32x4 accO[2][4] = {};
  float m_used[2] = {-3e38f, -3e38f}, m_true[2] = {-3e38f, -3e38f};
  float l_i[2] = {0.f, 0.f}, den[2] = {0.f, 0.f};

  __syncthreads();

  for (int kk = 0; kk < 64; ++kk) {
    const int buf = kk & 1;
    if (kk < 63) {
      const size_t key0n = (size_t)(kk + 1) * 64;
      #pragma unroll
      for (int j = 0; j < 2; ++j) {
        gll16(gk + (key0n + j * 8) * HID, &Ks[buf ^ 1][(w * 16 + j * 8) * 64]);
        gll16(gv + key0n + (size_t)(j * 8) * SEQ,
              &Vs[buf ^ 1][(w * 16 + j * 8) * 64]);
      }
    }

    bf16x8 ak[4][2];
    #pragma unroll
    for (int mt = 0; mt < 4; ++mt)
      #pragma unroll
      for (int ks = 0; ks < 2; ++ks)
        ak[mt][ks] = *(const bf16x8*)&Ks[buf][(mt * 16 + fr) * 64 +
                                             ((ks * 4 + quad + fr) & 7) * 8];

    f32x4 s[2][4];
    #pragma unroll
    for (int qf = 0; qf < 2; ++qf)
      #pragma unroll
      for (int mt = 0; mt < 4; ++mt) {
        f32x4 z = {};
        z = __builtin_amdgcn_mfma_f32_16x16x32_bf16(ak[mt][0], bq[qf][0], z, 0, 0, 0);
        z = __builtin_amdgcn_mfma_f32_16x16x32_bf16(ak[mt][1], bq[qf][1], z, 0, 0, 0);
        s[qf][mt] = z;
      }

    bf16x8 bp[2][2];
    #pragma unroll
    for (int qf = 0; qf < 2; ++qf) {
      float mx0 = fmaxf(fmaxf(s[qf][0][0], s[qf][0][1]), fmaxf(s[qf][0][2], s[qf][0][3]));
      float mx1 = fmaxf(fmaxf(s[qf][1][0], s[qf][1][1]), fmaxf(s[qf][1][2], s[qf][1][3]));
      float mx2 = fmaxf(fmaxf(s[qf][2][0], s[qf][2][1]), fmaxf(s[qf][2][2], s[qf][2][3]));
      float mx3 = fmaxf(fmaxf(s[qf][3][0], s[qf][3][1]), fmaxf(s[qf][3][2], s[qf][3][3]));
      float mx = fmaxf(fmaxf(mx0, mx1), fmaxf(mx2, mx3));
      mx = fmaxf(mx, __shfl_xor(mx, 16));
      mx = fmaxf(mx, __shfl_xor(mx, 32));
      m_true[qf] = fmaxf(m_true[qf], mx);

      if (__any(mx > m_used[qf] + THR_L2)) {
        const float mn = fmaxf(m_used[qf], mx);
        const float a = fast_exp2(m_used[qf] - mn);
        m_used[qf] = mn;
        l_i[qf] *= a;
        #pragma unroll
        for (int dt = 0; dt < 4; ++dt) accO[qf][dt] *= a;
      }

      float sum = 0.f;
      const int prow = fr * 64;
      #pragma unroll
      for (int mt = 0; mt < 4; ++mt) {
        float p0 = fast_exp2(s[qf][mt][0] - m_used[qf]);
        float p1 = fast_exp2(s[qf][mt][1] - m_used[qf]);
        float p2 = fast_exp2(s[qf][mt][2] - m_used[qf]);
        float p3 = fast_exp2(s[qf][mt][3] - m_used[qf]);
        sum += (p0 + p1) + (p2 + p3);
        bf16x4 pv = {(bf16)p0, (bf16)p1, (bf16)p2, (bf16)p3};
        *(bf16x4*)&Ps[w][prow + ((mt * 2 + (quad >> 1) + fr) & 7) * 8 +
                         (quad & 1) * 4] = pv;
      }
      sum += __shfl_xor(sum, 16);
      sum += __shfl_xor(sum, 32);
      l_i[qf] += sum;

      #pragma unroll
      for (int ks = 0; ks < 2; ++ks)
        bp[qf][ks] = *(const bf16x8*)&Ps[w][fr * 64 +
                                            ((ks * 4 + quad + fr) & 7) * 8];
    }

    #pragma unroll
    for (int ks = 0; ks < 2; ++ks)
      #pragma unroll
      for (int dt = 0; dt < 4; ++dt) {
        bf16x8 av = *(const bf16x8*)&Vs[buf][(dt * 16 + fr) * 64 +
                                            ((ks * 4 + quad + fr) & 7) * 8];
        accO[0][dt] = __builtin_amdgcn_mfma_f32_16x16x32_bf16(av, bp[0][ks], accO[0][dt], 0, 0, 0);
        accO[1][dt] = __builtin_amdgcn_mfma_f32_16x16x32_bf16(av, bp[1][ks], accO[1][dt], 0, 0, 0);
      }

    if ((kk & 15) == 15) {
      #pragma unroll
      for (int qf = 0; qf < 2; ++qf) {
        const float c = fast_exp2(m_used[qf] - m_true[qf]);
        den[qf] += l_i[qf] * c;
        #pragma unroll
        for (int dt = 0; dt < 4; ++dt)
          #pragma unroll
          for (int r = 0; r < 4; ++r) accN[qf][dt][r] += accO[qf][dt][r] * c;
        #pragma unroll
        for (int dt = 0; dt < 4; ++dt) accO[qf][dt] = (f32x4){0.f, 0.f, 0.f, 0.f};
        l_i[qf] = 0.f; m_used[qf] = -3e38f; m_true[qf] = -3e38f;
      }
    }
    __syncthreads();
  }

  #pragma unroll
  for (int qf = 0; qf < 2; ++qf) {
    const float inv = 1.0f / den[qf];
    const size_t orow = (size_t)(q0 + w * 32 + qf * 16 + fr) * HID + h * 64;
    #pragma unroll
    for (int dt = 0; dt < 4; ++dt) {
      bf16x4 ov = {(bf16)(accN[qf][dt][0] * inv), (bf16)(accN[qf][dt][1] * inv),
                   (bf16)(accN[qf][dt][2] * inv), (bf16)(accN[qf][dt][3] * inv)};
      *(bf16x4*)&O[orow + dt * 16 + quad * 4] = ov;
    }
  }
}

extern "C" void kernel_launch(void* const* d_in, const int* in_sizes, int n_in,
                              void* d_out, int out_size, void* d_ws, size_t ws_size,
                              hipStream_t stream)
{
  const float* X  = (const float*)d_in[0];
  const float* Wq = (const float*)d_in[1];
  const float* Wk = (const float*)d_in[2];
  const float* Wv = (const float*)d_in[3];
  const float* Wo = (const float*)d_in[4];
  float* out = (float*)d_out;

  const size_t MB = 1024 * 1024;
  bf16*  Xb  = (bf16*)d_ws;                       // 8 MB
  bf16*  Wt  = (bf16*)((char*)d_ws + 8  * MB);    // 4 x 2 MB
  bf16*  Qg  = (bf16*)((char*)d_ws + 16 * MB);    // 8 MB
  bf16*  Kg  = (bf16*)((char*)d_ws + 24 * MB);    // 8 MB
  bf16*  Vtg = (bf16*)((char*)d_ws + 32 * MB);    // 8 MB, [hid][seq]
  bf16*  Og  = (bf16*)((char*)d_ws + 40 * MB);    // 8 MB
  bf16*  Opart = (bf16*)((char*)d_ws + 48 * MB);  // 32 MB lane-major partials
  float* Den   = (float*)((char*)d_ws + 80 * MB); // 1 MB fp32

  prep_kernel<<<dim3(256, 1, 5), 256, 0, stream>>>(X, Wq, Wk, Wv, Wo, Xb, Wt);
  qkv_gemm<<<dim3(HID / 128, SEQ / 128, 3), 256, 0, stream>>>(Xb, Wt, Qg, Kg, Vtg);
  if (ws_size >= 81 * MB) {
    attn15<<<dim3(SEQ / 128, NHEADS, 4), 256, 0, stream>>>(Qg, Kg, Vtg, Opart, Den);
    combine8<<<dim3(SEQ / 32, NHEADS), 64, 0, stream>>>(Opart, Den, Og);
  } else {
    attn5<<<dim3(SEQ / 128, NHEADS), 256, 0, stream>>>(Qg, Kg, Vtg, Og);
  }
  oproj_gemm<<<dim3(HID / 128, SEQ / 64), 256, 0, stream>>>(
      Og, Wt + (size_t)3 * HID * HID, out);
}

// Round 17
// 234.732 us; speedup vs baseline: 2.3644x; 1.0033x over previous
//
#include <hip/hip_runtime.h>
#include <hip/hip_bf16.h>

typedef __bf16 bf16;
typedef bf16 bf16x2 __attribute__((ext_vector_type(2)));
typedef bf16 bf16x4 __attribute__((ext_vector_type(4)));
typedef bf16 bf16x8 __attribute__((ext_vector_type(8)));
typedef float f32x4 __attribute__((ext_vector_type(4)));
typedef float f32x16 __attribute__((ext_vector_type(16)));
typedef unsigned int u32x4 __attribute__((ext_vector_type(4)));

#define HID 1024
#define NHEADS 16
#define HD 64
#define SEQ 4096

__device__ __forceinline__ void gll16(const void* g, void* l) {
  __builtin_amdgcn_global_load_lds(
      (const __attribute__((address_space(1))) void*)g,
      (__attribute__((address_space(3))) void*)l, 16, 0, 0);
}

__device__ __forceinline__ float fast_exp2(float x) {
#if __has_builtin(__builtin_amdgcn_exp2f)
  return __builtin_amdgcn_exp2f(x);
#else
  return __expf(x * 0.6931471805599453f);
#endif
}

// gfx950 half-wave swap: X' = [X.lo | Y.lo], Y' = [X.hi | Y.hi]
__device__ __forceinline__ void pl32swap(unsigned& a, unsigned& b) {
  asm volatile("v_permlane32_swap_b32 %0, %1" : "+v"(a), "+v"(b));
}

// ---------------------------------------------------------------------------
// Prep: z=0 convert X fp32->bf16; z=1..4 transpose+convert W -> Wt[out][in].
// Attention scale folded into Wq in LOG2 domain: 0.125 * log2(e).
// ---------------------------------------------------------------------------
__global__ __launch_bounds__(256)
void prep_kernel(const float* __restrict__ X,
                 const float* __restrict__ Wq, const float* __restrict__ Wk,
                 const float* __restrict__ Wv, const float* __restrict__ Wo,
                 bf16* __restrict__ Xb, bf16* __restrict__ Wt)
{
  const int z = blockIdx.z, t = threadIdx.x, bx = blockIdx.x;
  if (z == 0) {
    const float4* src = (const float4*)X;
    const int gid = bx * 256 + t;
    #pragma unroll
    for (int i = 0; i < 16; ++i) {
      float4 v = src[gid + i * 65536];
      bf16x4 o = {(bf16)v.x, (bf16)v.y, (bf16)v.z, (bf16)v.w};
      *(bf16x4*)&Xb[(size_t)(gid + i * 65536) * 4] = o;
    }
  } else {
    const float* W = (z == 1) ? Wq : (z == 2) ? Wk : (z == 3) ? Wv : Wo;
    bf16* dst = Wt + (size_t)(z - 1) * HID * HID;
    const float scale = (z == 1) ? 0.18033688011112042f : 1.0f;  // 0.125*log2(e)
    __shared__ bf16 T[64][68];
    const int tr = (bx >> 4) * 64, tc = (bx & 15) * 64;
    #pragma unroll
    for (int p = 0; p < 4; ++p) {
      int row = (t >> 4) + p * 16;
      float4 v = *(const float4*)&W[(size_t)(tr + row) * HID + tc + (t & 15) * 4];
      T[row][(t & 15) * 4 + 0] = (bf16)(v.x * scale);
      T[row][(t & 15) * 4 + 1] = (bf16)(v.y * scale);
      T[row][(t & 15) * 4 + 2] = (bf16)(v.z * scale);
      T[row][(t & 15) * 4 + 3] = (bf16)(v.w * scale);
    }
    __syncthreads();
    #pragma unroll
    for (int p = 0; p < 4; ++p) {
      int rp = (t >> 4) + p * 16;
      int cb = (t & 15) * 4;
      bf16x4 o = {T[cb + 0][rp], T[cb + 1][rp], T[cb + 2][rp], T[cb + 3][rp]};
      *(bf16x4*)&dst[(size_t)(tc + rp) * HID + tr + cb] = o;
    }
  }
}

// ---------------------------------------------------------------------------
// QKV GEMM v2: C = Xb[M,K] @ Wt[z][N,K]^T. 64x128 tile (M-split, same lever
// as oproj v2): grid (8,64,3) = 1536 blocks = 6 blocks/CU (was 3) -> barrier
// drains hidden by co-resident blocks. Waves 2x2: each 32x64 (acc[2][4]).
// A-tile 64x64 (2 chunks/wave), B-tile 128x64 (4 chunks/wave), LDS 24 KB.
// z=2 writes V transposed via swizzled LDS transpose re-derived for 64-col
// tile: colS = (col + 8*(row&15)) & 63 (multiples of 8 mod 64 -> bf16x8
// reads never wrap).
// ---------------------------------------------------------------------------
__global__ __launch_bounds__(256)
void qkv_gemm(const bf16* __restrict__ A, const bf16* __restrict__ Wt,
              bf16* __restrict__ Qg, bf16* __restrict__ Kg,
              bf16* __restrict__ Vt)
{
  __shared__ bf16 sbuf[12288];
  bf16* As = sbuf;           // 64 x 64
  bf16* Bs = sbuf + 4096;    // 128 x 64

  const int t = threadIdx.x, lane = t & 63, w = t >> 6;
  const int z = blockIdx.z;
  const int n0 = blockIdx.x * 128, m0 = blockIdx.y * 64;
  const bf16* Bt = Wt + (size_t)z * HID * HID;
  const int wm = (w & 1) * 32, wn = (w >> 1) * 64;
  const int fr = lane & 15, quad = lane >> 4;

  f32x4 acc[2][4] = {};

  const int sr = lane >> 3;              // 0..7
  const int sc = ((lane & 7) - sr) & 7;  // rotated chunk
  const bf16* ga = A  + (size_t)(m0 + w * 16 + sr) * HID + sc * 8;
  const bf16* gb = Bt + (size_t)(n0 + w * 32 + sr) * HID + sc * 8;

  for (int k0 = 0; k0 < HID; k0 += 64) {
    __syncthreads();
    #pragma unroll
    for (int c = 0; c < 2; ++c)
      gll16(ga + (size_t)(c * 8) * HID + k0, As + (w * 16 + c * 8) * 64);
    #pragma unroll
    for (int c = 0; c < 4; ++c)
      gll16(gb + (size_t)(c * 8) * HID + k0, Bs + (w * 32 + c * 8) * 64);
    __syncthreads();
    #pragma unroll
    for (int ks = 0; ks < 2; ++ks) {
      bf16x8 af[2], bg[4];
      #pragma unroll
      for (int i = 0; i < 2; ++i)
        af[i] = *(const bf16x8*)&As[(wm + i * 16 + fr) * 64 +
                                    ((ks * 4 + quad + fr) & 7) * 8];
      #pragma unroll
      for (int i = 0; i < 4; ++i)
        bg[i] = *(const bf16x8*)&Bs[(wn + i * 16 + fr) * 64 +
                                    ((ks * 4 + quad + fr) & 7) * 8];
      #pragma unroll
      for (int mi = 0; mi < 2; ++mi)
        #pragma unroll
        for (int ni = 0; ni < 4; ++ni)
          acc[mi][ni] = __builtin_amdgcn_mfma_f32_16x16x32_bf16(
              af[mi], bg[ni], acc[mi][ni], 0, 0, 0);
    }
  }

  if (z < 2) {
    bf16* C = z ? Kg : Qg;
    #pragma unroll
    for (int mi = 0; mi < 2; ++mi)
      #pragma unroll
      for (int ni = 0; ni < 4; ++ni)
        #pragma unroll
        for (int r = 0; r < 4; ++r)
          C[(size_t)(m0 + wm + mi * 16 + quad * 4 + r) * HID +
            n0 + wn + ni * 16 + fr] = (bf16)acc[mi][ni][r];
  } else {
    __syncthreads();
    // swizzled transpose (64-col tile): col stored at (col + 8*(row&15)) & 63
    #pragma unroll
    for (int mi = 0; mi < 2; ++mi)
      #pragma unroll
      for (int ni = 0; ni < 4; ++ni)
        #pragma unroll
        for (int r = 0; r < 4; ++r) {
          int row = wn + ni * 16 + fr;                 // n in [0,128)
          int col = wm + mi * 16 + quad * 4 + r;       // m in [0,64)
          int colS = (col + 8 * (row & 15)) & 63;
          sbuf[row * 64 + colS] = (bf16)acc[mi][ni][r];
        }
    __syncthreads();
    const int row = t >> 1, cb = (t & 1) * 32;
    #pragma unroll
    for (int j = 0; j < 4; ++j) {
      int c0 = (cb + j * 8 + 8 * (row & 15)) & 63;
      *(bf16x8*)&Vt[(size_t)(n0 + row) * SEQ + m0 + cb + j * 8] =
          *(const bf16x8*)&sbuf[row * 64 + c0];
    }
  }
}

// ---------------------------------------------------------------------------
// O-projection v2 (r15-verified): 64x128 tile, 2 blocks/CU.
// ---------------------------------------------------------------------------
__global__ __launch_bounds__(256)
void oproj_gemm(const bf16* __restrict__ A, const bf16* __restrict__ Bt,
                float* __restrict__ C)
{
  __shared__ bf16 sbuf[12288];
  bf16* As = sbuf;           // 64 x 64
  bf16* Bs = sbuf + 4096;    // 128 x 64

  const int t = threadIdx.x, lane = t & 63, w = t >> 6;
  const int n0 = blockIdx.x * 128, m0 = blockIdx.y * 64;
  const int wm = (w & 1) * 32, wn = (w >> 1) * 64;
  const int fr = lane & 15, quad = lane >> 4;

  f32x4 acc[2][4] = {};

  const int sr = lane >> 3;
  const int sc = ((lane & 7) - sr) & 7;
  const bf16* ga = A  + (size_t)(m0 + w * 16 + sr) * HID + sc * 8;
  const bf16* gb = Bt + (size_t)(n0 + w * 32 + sr) * HID + sc * 8;

  for (int k0 = 0; k0 < HID; k0 += 64) {
    __syncthreads();
    #pragma unroll
    for (int c = 0; c < 2; ++c)
      gll16(ga + (size_t)(c * 8) * HID + k0, As + (w * 16 + c * 8) * 64);
    #pragma unroll
    for (int c = 0; c < 4; ++c)
      gll16(gb + (size_t)(c * 8) * HID + k0, Bs + (w * 32 + c * 8) * 64);
    __syncthreads();
    #pragma unroll
    for (int ks = 0; ks < 2; ++ks) {
      bf16x8 af[2], bg[4];
      #pragma unroll
      for (int i = 0; i < 2; ++i)
        af[i] = *(const bf16x8*)&As[(wm + i * 16 + fr) * 64 +
                                    ((ks * 4 + quad + fr) & 7) * 8];
      #pragma unroll
      for (int i = 0; i < 4; ++i)
        bg[i] = *(const bf16x8*)&Bs[(wn + i * 16 + fr) * 64 +
                                    ((ks * 4 + quad + fr) & 7) * 8];
      #pragma unroll
      for (int mi = 0; mi < 2; ++mi)
        #pragma unroll
        for (int ni = 0; ni < 4; ++ni)
          acc[mi][ni] = __builtin_amdgcn_mfma_f32_16x16x32_bf16(
              af[mi], bg[ni], acc[mi][ni], 0, 0, 0);
    }
  }

  #pragma unroll
  for (int mi = 0; mi < 2; ++mi)
    #pragma unroll
    for (int ni = 0; ni < 4; ++ni)
      #pragma unroll
      for (int r = 0; r < 4; ++r)
        C[(size_t)(m0 + wm + mi * 16 + quad * 4 + r) * HID +
          n0 + wn + ni * 16 + fr] = acc[mi][ni][r];
}

// ---------------------------------------------------------------------------
// Attention v15 (verified 88.7 us): 32x32 structure, exp2-direct softmax,
// den-on-MFMA, permlane32 exchange, setprio around MFMA clusters.
// ---------------------------------------------------------------------------
__global__ __launch_bounds__(256, 4)
void attn15(const bf16* __restrict__ Q, const bf16* __restrict__ K,
            const bf16* __restrict__ Vt, bf16* __restrict__ Opart,
            float* __restrict__ Den)
{
  __shared__ bf16 Ks[2][4096];
  __shared__ bf16 Vs[2][4096];

  const int t = threadIdx.x, lane = t & 63, w = t >> 6;
  const int h = blockIdx.y, q0 = blockIdx.x * 128, qtr = blockIdx.z;
  const int q = lane & 31, hi = lane >> 5;
  const int qrow = q0 + w * 32 + q;

  // Q B-fragments: bq[j] = Q[qrow][h*64 + j*16 + hi*8 .. +8]
  bf16x8 bq[4];
  #pragma unroll
  for (int j = 0; j < 4; ++j)
    bq[j] = *(const bf16x8*)&Q[(size_t)qrow * HID + h * 64 + j * 16 + hi * 8];

  const bf16 onev = (bf16)1.0f;
  const bf16x8 ones = {onev, onev, onev, onev, onev, onev, onev, onev};

  const int sr = lane >> 3;
  const int sc = ((lane & 7) - sr) & 7;
  const bf16* gk = K  + (size_t)(qtr * 1024 + w * 16 + sr) * HID + h * 64 + sc * 8;
  const bf16* gv = Vt + (size_t)(h * 64 + w * 16 + sr) * SEQ + qtr * 1024 + sc * 8;

  #pragma unroll
  for (int j = 0; j < 2; ++j) {
    gll16(gk + (size_t)(j * 8) * HID, &Ks[0][(w * 16 + j * 8) * 64]);
    gll16(gv + (size_t)(j * 8) * SEQ, &Vs[0][(w * 16 + j * 8) * 64]);
  }

  f32x16 accO[2], accD;
  #pragma unroll
  for (int r = 0; r < 16; ++r) { accO[0][r] = 0.f; accO[1][r] = 0.f; accD[r] = 0.f; }
  float m4[4] = {-3e38f, -3e38f, -3e38f, -3e38f};

  __syncthreads();

  for (int kk = 0; kk < 16; ++kk) {
    const int buf = kk & 1;
    if (kk < 15) {
      const size_t key0n = (size_t)(kk + 1) * 64;
      #pragma unroll
      for (int j = 0; j < 2; ++j) {
        gll16(gk + (key0n + j * 8) * HID, &Ks[buf ^ 1][(w * 16 + j * 8) * 64]);
        gll16(gv + key0n + (size_t)(j * 8) * SEQ,
              &Vs[buf ^ 1][(w * 16 + j * 8) * 64]);
      }
    }

    #pragma unroll
    for (int st = 0; st < 2; ++st) {
      const int r0 = st * 32;         // key sub-tile base row
      // QK^T: 4 chained mfma over d (k=16 each)
      f32x16 s;
      #pragma unroll
      for (int r = 0; r < 16; ++r) s[r] = 0.f;
      __builtin_amdgcn_s_setprio(1);
      #pragma unroll
      for (int j = 0; j < 4; ++j) {
        const int row = r0 + q;
        bf16x8 ak = *(const bf16x8*)&Ks[buf][row * 64 +
                                            ((j * 2 + hi + row) & 7) * 8];
        s = __builtin_amdgcn_mfma_f32_32x32x16_bf16(ak, bq[j], s, 0, 0, 0);
      }
      __builtin_amdgcn_s_setprio(0);

      // running block-max: 3-input max chains (v_max3)
      #pragma unroll
      for (int r = 0; r < 16; r += 4) {
        m4[0] = fmaxf(fmaxf(m4[0], s[r]), s[r + 1]);
        m4[1] = fmaxf(fmaxf(m4[1], s[r + 2]), s[r + 3]);
      }

      // P = exp2(s) directly; den handled by MFMA below
      float p[16];
      #pragma unroll
      for (int r = 0; r < 16; ++r) p[r] = fast_exp2(s[r]);

      unsigned pk[8];
      #pragma unroll
      for (int i = 0; i < 8; ++i) {
        bf16x2 pp = {(bf16)p[2 * i], (bf16)p[2 * i + 1]};
        pk[i] = __builtin_bit_cast(unsigned, pp);
      }
      // half-wave exchange on VALU: post-swap pk[] is the fragment verbatim
      pl32swap(pk[0], pk[2]);
      pl32swap(pk[1], pk[3]);
      pl32swap(pk[4], pk[6]);
      pl32swap(pk[5], pk[7]);
      u32x4 w0 = {pk[0], pk[1], pk[2], pk[3]};
      u32x4 w1 = {pk[4], pk[5], pk[6], pk[7]};
      bf16x8 bp0 = __builtin_bit_cast(bf16x8, w0);
      bf16x8 bp1 = __builtin_bit_cast(bf16x8, w1);

      __builtin_amdgcn_s_setprio(1);
      // den on the MFMA pipe: every row of accD = sum_k P[q][k]
      accD = __builtin_amdgcn_mfma_f32_32x32x16_bf16(ones, bp0, accD, 0, 0, 0);
      accD = __builtin_amdgcn_mfma_f32_32x32x16_bf16(ones, bp1, accD, 0, 0, 0);

      // PV: O^T[db] += V^T . P^T  (k = keys, 2 chunks of 16)
      #pragma unroll
      for (int db = 0; db < 2; ++db) {
        const int rowd = db * 32 + q;
        bf16x8 av0 = *(const bf16x8*)&Vs[buf][rowd * 64 +
                       ((st * 4 + 0 + hi + rowd) & 7) * 8];
        accO[db] = __builtin_amdgcn_mfma_f32_32x32x16_bf16(av0, bp0, accO[db], 0, 0, 0);
        bf16x8 av1 = *(const bf16x8*)&Vs[buf][rowd * 64 +
                       ((st * 4 + 2 + hi + rowd) & 7) * 8];
        accO[db] = __builtin_amdgcn_mfma_f32_32x32x16_bf16(av1, bp1, accO[db], 0, 0, 0);
      }
      __builtin_amdgcn_s_setprio(0);
    }
    __syncthreads();
  }

  // epilogue: merge block max, lane-major locally-normalized partial + den
  {
    const float l = accD[0];
    float m_true = fmaxf(fmaxf(m4[0], m4[1]), fmaxf(m4[2], m4[3]));
    m_true = fmaxf(m_true, __shfl_xor(m_true, 32));
    const float inv = 1.0f / l;
    const size_t base =
        ((size_t)(qtr * 16 + h) * 128 + (q0 >> 5) + w) * 2048 + (size_t)lane * 32;
    #pragma unroll
    for (int j = 0; j < 4; ++j) {
      bf16x8 wv;
      #pragma unroll
      for (int e = 0; e < 8; ++e)
        wv[e] = (bf16)(accO[j >> 1][(j & 1) * 8 + e] * inv);
      *(bf16x8*)&Opart[base + j * 8] = wv;
    }
    if (hi == 0)
      Den[(size_t)(qtr * 16 + h) * SEQ + qrow] = l * fast_exp2(-m_true);
  }
}

// ---------------------------------------------------------------------------
// Combine8: one wave per (h, 32-query seg). Reads 4 lane-major partials
// (coalesced), weights by den_rb / sum(den), LDS-transposes reg layout
// (d = db*32 + (r&3) + 8*(r>>2) + 4*hi) to [q][d], writes Og coalesced.
// ---------------------------------------------------------------------------
__global__ __launch_bounds__(64)
void combine8(const bf16* __restrict__ Opart, const float* __restrict__ Den,
              bf16* __restrict__ Og)
{
  __shared__ bf16 T[32][72];
  const int lane = threadIdx.x & 63;
  const int h = blockIdx.y, qs = blockIdx.x;   // qs in [0,128)
  const int q = lane & 31, hi = lane >> 5;

  float dw[4];
  #pragma unroll
  for (int rb = 0; rb < 4; ++rb)
    dw[rb] = Den[(size_t)(rb * 16 + h) * SEQ + qs * 32 + q];
  const float inv = 1.0f / (dw[0] + dw[1] + dw[2] + dw[3]);

  float acc[32];
  #pragma unroll
  for (int i = 0; i < 32; ++i) acc[i] = 0.f;
  #pragma unroll
  for (int rb = 0; rb < 4; ++rb) {
    const float wq = dw[rb] * inv;
    const size_t base =
        ((size_t)(rb * 16 + h) * 128 + qs) * 2048 + (size_t)lane * 32;
    #pragma unroll
    for (int j = 0; j < 4; ++j) {
      bf16x8 v = *(const bf16x8*)&Opart[base + j * 8];
      #pragma unroll
      for (int e = 0; e < 8; ++e) acc[j * 8 + e] += wq * (float)v[e];
    }
  }

  #pragma unroll
  for (int idx = 0; idx < 32; ++idx) {
    const int db = idx >> 4, r = idx & 15;
    const int d = db * 32 + (r & 3) + 8 * (r >> 2) + 4 * hi;
    T[q][d] = (bf16)acc[idx];
  }
  __syncthreads();
  #pragma unroll
  for (int p = 0; p < 4; ++p) {
    const int row = p * 8 + (lane >> 3);
    *(bf16x8*)&Og[(size_t)(qs * 32 + row) * HID + h * 64 + (lane & 7) * 8] =
        *(const bf16x8*)&T[row][(lane & 7) * 8];
  }
}

// ---------------------------------------------------------------------------
// Attention v5 (fallback if workspace < 81 MB): round-3-verified.
// ---------------------------------------------------------------------------
#define THR_L2 12.0f

__global__ __launch_bounds__(256, 2)
void attn5(const bf16* __restrict__ Q, const bf16* __restrict__ K,
           const bf16* __restrict__ Vt, bf16* __restrict__ O)
{
  __shared__ bf16 Ks[2][4096];
  __shared__ bf16 Vs[2][4096];
  __shared__ bf16 Ps[4][1024];

  const int t = threadIdx.x, lane = t & 63, w = t >> 6;
  const int h = blockIdx.y, q0 = blockIdx.x * 128;
  const int fr = lane & 15, quad = lane >> 4;

  bf16x8 bq[2][2];
  #pragma unroll
  for (int qf = 0; qf < 2; ++qf)
    #pragma unroll
    for (int ks = 0; ks < 2; ++ks)
      bq[qf][ks] = *(const bf16x8*)&Q[(size_t)(q0 + w * 32 + qf * 16 + fr) * HID
                                      + h * 64 + ks * 32 + quad * 8];

  const int sr = lane >> 3;
  const int sc = ((lane & 7) - sr) & 7;
  const bf16* gk = K  + (size_t)(w * 16 + sr) * HID + h * 64 + sc * 8;
  const bf16* gv = Vt + (size_t)(h * 64 + w * 16 + sr) * SEQ + sc * 8;

  #pragma unroll
  for (int j = 0; j < 2; ++j) {
    gll16(gk + (size_t)(j * 8) * HID, &Ks[0][(w * 16 + j * 8) * 64]);
    gll16(gv + (size_t)(j * 8) * SEQ, &Vs[0][(w * 16 + j * 8) * 64]);
  }

  f32x4 accN[2][4] = {};
  f32x4 accO[2][4] = {};
  float m_used[2] = {-3e38f, -3e38f}, m_true[2] = {-3e38f, -3e38f};
  float l_i[2] = {0.f, 0.f}, den[2] = {0.f, 0.f};

  __syncthreads();

  for (int kk = 0; kk < 64; ++kk) {
    const int buf = kk & 1;
    if (kk < 63) {
      const size_t key0n = (size_t)(kk + 1) * 64;
      #pragma unroll
      for (int j = 0; j < 2; ++j) {
        gll16(gk + (key0n + j * 8) * HID, &Ks[buf ^ 1][(w * 16 + j * 8) * 64]);
        gll16(gv + key0n + (size_t)(j * 8) * SEQ,
              &Vs[buf ^ 1][(w * 16 + j * 8) * 64]);
      }
    }

    bf16x8 ak[4][2];
    #pragma unroll
    for (int mt = 0; mt < 4; ++mt)
      #pragma unroll
      for (int ks = 0; ks < 2; ++ks)
        ak[mt][ks] = *(const bf16x8*)&Ks[buf][(mt * 16 + fr) * 64 +
                                             ((ks * 4 + quad + fr) & 7) * 8];

    f32x4 s[2][4];
    #pragma unroll
    for (int qf = 0; qf < 2; ++qf)
      #pragma unroll
      for (int mt = 0; mt < 4; ++mt) {
        f32x4 z = {};
        z = __builtin_amdgcn_mfma_f32_16x16x32_bf16(ak[mt][0], bq[qf][0], z, 0, 0, 0);
        z = __builtin_amdgcn_mfma_f32_16x16x32_bf16(ak[mt][1], bq[qf][1], z, 0, 0, 0);
        s[qf][mt] = z;
      }

    bf16x8 bp[2][2];
    #pragma unroll
    for (int qf = 0; qf < 2; ++qf) {
      float mx0 = fmaxf(fmaxf(s[qf][0][0], s[qf][0][1]), fmaxf(s[qf][0][2], s[qf][0][3]));
      float mx1 = fmaxf(fmaxf(s[qf][1][0], s[qf][1][1]), fmaxf(s[qf][1][2], s[qf][1][3]));
      float mx2 = fmaxf(fmaxf(s[qf][2][0], s[qf][2][1]), fmaxf(s[qf][2][2], s[qf][2][3]));
      float mx3 = fmaxf(fmaxf(s[qf][3][0], s[qf][3][1]), fmaxf(s[qf][3][2], s[qf][3][3]));
      float mx = fmaxf(fmaxf(mx0, mx1), fmaxf(mx2, mx3));
      mx = fmaxf(mx, __shfl_xor(mx, 16));
      mx = fmaxf(mx, __shfl_xor(mx, 32));
      m_true[qf] = fmaxf(m_true[qf], mx);

      if (__any(mx > m_used[qf] + THR_L2)) {
        const float mn = fmaxf(m_used[qf], mx);
        const float a = fast_exp2(m_used[qf] - mn);
        m_used[qf] = mn;
        l_i[qf] *= a;
        #pragma unroll
        for (int dt = 0; dt < 4; ++dt) accO[qf][dt] *= a;
      }

      float sum = 0.f;
      const int prow = fr * 64;
      #pragma unroll
      for (int mt = 0; mt < 4; ++mt) {
        float p0 = fast_exp2(s[qf][mt][0] - m_used[qf]);
        float p1 = fast_exp2(s[qf][mt][1] - m_used[qf]);
        float p2 = fast_exp2(s[qf][mt][2] - m_used[qf]);
        float p3 = fast_exp2(s[qf][mt][3] - m_used[qf]);
        sum += (p0 + p1) + (p2 + p3);
        bf16x4 pv = {(bf16)p0, (bf16)p1, (bf16)p2, (bf16)p3};
        *(bf16x4*)&Ps[w][prow + ((mt * 2 + (quad >> 1) + fr) & 7) * 8 +
                         (quad & 1) * 4] = pv;
      }
      sum += __shfl_xor(sum, 16);
      sum += __shfl_xor(sum, 32);
      l_i[qf] += sum;

      #pragma unroll
      for (int ks = 0; ks < 2; ++ks)
        bp[qf][ks] = *(const bf16x8*)&Ps[w][fr * 64 +
                                            ((ks * 4 + quad + fr) & 7) * 8];
    }

    #pragma unroll
    for (int ks = 0; ks < 2; ++ks)
      #pragma unroll
      for (int dt = 0; dt < 4; ++dt) {
        bf16x8 av = *(const bf16x8*)&Vs[buf][(dt * 16 + fr) * 64 +
                                            ((ks * 4 + quad + fr) & 7) * 8];
        accO[0][dt] = __builtin_amdgcn_mfma_f32_16x16x32_bf16(av, bp[0][ks], accO[0][dt], 0, 0, 0);
        accO[1][dt] = __builtin_amdgcn_mfma_f32_16x16x32_bf16(av, bp[1][ks], accO[1][dt], 0, 0, 0);
      }

    if ((kk & 15) == 15) {
      #pragma unroll
      for (int qf = 0; qf < 2; ++qf) {
        const float c = fast_exp2(m_used[qf] - m_true[qf]);
        den[qf] += l_i[qf] * c;
        #pragma unroll
        for (int dt = 0; dt < 4; ++dt)
          #pragma unroll
          for (int r = 0; r < 4; ++r) accN[qf][dt][r] += accO[qf][dt][r] * c;
        #pragma unroll
        for (int dt = 0; dt < 4; ++dt) accO[qf][dt] = (f32x4){0.f, 0.f, 0.f, 0.f};
        l_i[qf] = 0.f; m_used[qf] = -3e38f; m_true[qf] = -3e38f;
      }
    }
    __syncthreads();
  }

  #pragma unroll
  for (int qf = 0; qf < 2; ++qf) {
    const float inv = 1.0f / den[qf];
    const size_t orow = (size_t)(q0 + w * 32 + qf * 16 + fr) * HID + h * 64;
    #pragma unroll
    for (int dt = 0; dt < 4; ++dt) {
      bf16x4 ov = {(bf16)(accN[qf][dt][0] * inv), (bf16)(accN[qf][dt][1] * inv),
                   (bf16)(accN[qf][dt][2] * inv), (bf16)(accN[qf][dt][3] * inv)};
      *(bf16x4*)&O[orow + dt * 16 + quad * 4] = ov;
    }
  }
}

extern "C" void kernel_launch(void* const* d_in, const int* in_sizes, int n_in,
                              void* d_out, int out_size, void* d_ws, size_t ws_size,
                              hipStream_t stream)
{
  const float* X  = (const float*)d_in[0];
  const float* Wq = (const float*)d_in[1];
  const float* Wk = (const float*)d_in[2];
  const float* Wv = (const float*)d_in[3];
  const float* Wo = (const float*)d_in[4];
  float* out = (float*)d_out;

  const size_t MB = 1024 * 1024;
  bf16*  Xb  = (bf16*)d_ws;                       // 8 MB
  bf16*  Wt  = (bf16*)((char*)d_ws + 8  * MB);    // 4 x 2 MB
  bf16*  Qg  = (bf16*)((char*)d_ws + 16 * MB);    // 8 MB
  bf16*  Kg  = (bf16*)((char*)d_ws + 24 * MB);    // 8 MB
  bf16*  Vtg = (bf16*)((char*)d_ws + 32 * MB);    // 8 MB, [hid][seq]
  bf16*  Og  = (bf16*)((char*)d_ws + 40 * MB);    // 8 MB
  bf16*  Opart = (bf16*)((char*)d_ws + 48 * MB);  // 32 MB lane-major partials
  float* Den   = (float*)((char*)d_ws + 80 * MB); // 1 MB fp32

  prep_kernel<<<dim3(256, 1, 5), 256, 0, stream>>>(X, Wq, Wk, Wv, Wo, Xb, Wt);
  qkv_gemm<<<dim3(HID / 128, SEQ / 64, 3), 256, 0, stream>>>(Xb, Wt, Qg, Kg, Vtg);
  if (ws_size >= 81 * MB) {
    attn15<<<dim3(SEQ / 128, NHEADS, 4), 256, 0, stream>>>(Qg, Kg, Vtg, Opart, Den);
    combine8<<<dim3(SEQ / 32, NHEADS), 64, 0, stream>>>(Opart, Den, Og);
  } else {
    attn5<<<dim3(SEQ / 128, NHEADS), 256, 0, stream>>>(Qg, Kg, Vtg, Og);
  }
  oproj_gemm<<<dim3(HID / 128, SEQ / 64), 256, 0, stream>>>(
      Og, Wt + (size_t)3 * HID * HID, out);
}